// Round 13
// baseline (85.330 us; speedup 1.0000x reference)
//
#include <hip/hip_runtime.h>
#include <math.h>

#define NN 8
#define CC 256        // channels per tensor (concat input has 2*CC = 512)
#define HH 48
#define WW 48
#define HW 2304       // 48*48
#define OCONV 18      // offset-conv output channels (2*K)
#define KTAP 9        // deform taps
#define G1 8          // split-K groups for offset conv (512/8 = 64 ch/group)
#define NSZ (NN * OCONV * HW)   // 331776
#define MM 96         // padded deform-GEMM rows (81 used)
#define NCG 64        // 512 ch / 8
#define PPL 2704      // padded plane sites: 52*52 (2-site zero border)

typedef __attribute__((ext_vector_type(8))) short short8;   // 8 bf16 (4 VGPRs)
typedef __attribute__((ext_vector_type(16))) float f32x16;  // 32x32 MFMA acc

static __device__ __forceinline__ unsigned short f2bf(float f) {
  unsigned u = __float_as_uint(f);
  unsigned r = (u + 0x7fffu + ((u >> 16) & 1u)) >> 16;   // round-to-nearest-even
  return (unsigned short)r;
}

// ---------------------------------------------------------------------------
// Kernel 0: weight prep (merged).
// Blocks 0..1599: Wm3[g][kk][half][lane][t][8] (tap-innermost A-frags).
// Blocks 1600..1695: wkm A-frags (rows m=k*9+o, pad 96).
// ---------------------------------------------------------------------------
__global__ __launch_bounds__(256) void prep_weights(
    const float* __restrict__ w_off, const float* __restrict__ w_kernel,
    unsigned short* __restrict__ Wm3, unsigned short* __restrict__ wkm) {
  const int b = blockIdx.x;
  if (b < 1600) {
    const int i = b * 256 + threadIdx.x;      // < 409600
    const int j = i & 7;
    const int q = i >> 3;
    const int t = q % 25;
    const int r = q / 25;
    const int l    = r & 31;
    const int half = (r >> 5) & 1;
    const int kk   = (r >> 6) & 3;
    const int g    = r >> 8;                  // 0..7
    const int c = g * 64 + kk * 16 + half * 8 + j;
    float v = 0.f;
    if (l < OCONV) v = w_off[(size_t)(l * (2 * CC) + c) * 25 + t];
    Wm3[i] = f2bf(v);
  } else {
    const int i = (b - 1600) * 256 + threadIdx.x;
    if (i >= 3 * 16 * 2 * 32 * 8) return;
    const int j    = i & 7;
    const int r    = (i >> 3) & 31;
    const int half = (i >> 8) & 1;
    const int cb   = (i >> 9) & 15;
    const int mt   = i >> 13;
    const int m = mt * 32 + r;
    const int c = cb * 16 + half * 8 + j;
    float v = 0.f;
    if (m < 81) {
      const int k = m / 9, o = m % 9;
      v = w_kernel[(size_t)(o * CC + c) * KTAP + k];
    }
    wkm[i] = f2bf(v);
  }
}

// ---------------------------------------------------------------------------
// Kernel 1: transpose query+support -> qsT[n][cg][52x52 padded][8ch] bf16.
// Interior site (y,x) -> padded (y+2)*52+(x+2); 2-wide border zeroed by
// pt==0 blocks. XCD-pinned by n.
// ---------------------------------------------------------------------------
__global__ __launch_bounds__(256) void transpose_kernel(
    const float* __restrict__ support, const float* __restrict__ query,
    unsigned short* __restrict__ qsT) {
  const int bid = blockIdx.x;         // 9216 = 8n * 72pt * 16ct
  const int n    = bid & 7;           // XCD pin
  const int rest = bid >> 3;
  const int pt = rest % 72;
  const int ct = rest / 72;           // 0..15; 32-ch block
  const int p0 = pt * 32;
  const int tid = threadIdx.x;

  __shared__ float tile[32][33];

  const float* plane = ((ct < 8) ? query : support) +
                       ((size_t)n * CC + (ct & 7) * 32) * HW;
#pragma unroll
  for (int j = 0; j < 4; ++j) {
    const int idx = tid + j * 256;
    const int cc = idx >> 5, pp = idx & 31;
    tile[pp][cc] = plane[(size_t)cc * HW + p0 + pp];
  }
  __syncthreads();

  unsigned short* qn = qsT + (size_t)n * NCG * PPL * 8;
  const int cgbase = ((ct < 8) ? 0 : 32) + (ct & 7) * 4;

  if (tid < 128) {
    const int pp  = tid & 31;
    const int cgl = tid >> 5;          // 0..3
    const int s = p0 + pp;
    const int y = s / 48, x = s % 48;
    const int psite = (y + 2) * 52 + (x + 2);
    const float* row = &tile[pp][cgl * 8];
    uint4 w;
    w.x = (unsigned)f2bf(row[0]) | ((unsigned)f2bf(row[1]) << 16);
    w.y = (unsigned)f2bf(row[2]) | ((unsigned)f2bf(row[3]) << 16);
    w.z = (unsigned)f2bf(row[4]) | ((unsigned)f2bf(row[5]) << 16);
    w.w = (unsigned)f2bf(row[6]) | ((unsigned)f2bf(row[7]) << 16);
    *(uint4*)(qn + ((size_t)(cgbase + cgl) * PPL + psite) * 8) = w;
  }

  // zero border: 400 border sites x 4 cg planes, done by pt==0 blocks
  if (pt == 0) {
    const uint4 zz = make_uint4(0u, 0u, 0u, 0u);
    for (int z = tid; z < 1600; z += 256) {
      const int cgl = z / 400;
      const int e   = z % 400;
      int row, col;
      if (e < 104)      { row = e / 52;              col = e % 52; }          // rows 0,1
      else if (e < 208) { row = 50 + (e - 104) / 52; col = (e - 104) % 52; }  // rows 50,51
      else {
        const int f = e - 208;                                               // cols 0,1,50,51
        row = 2 + f / 4;
        const int cs = f % 4;
        col = (cs < 2) ? cs : (48 + cs);
      }
      *(uint4*)(qn + ((size_t)(cgbase + cgl) * PPL + row * 52 + col) * 8) = zz;
    }
  }
}

// ---------------------------------------------------------------------------
// Kernel 2: offset conv, no-LDS implicit GEMM with MANUAL register
// double-buffered prefetch: 25 taps split into 5 groups of 5; group tg+1's
// 15 fragments are loaded before group tg's MFMAs issue -> ~15 loads in
// flight per wave (vs ~1 when the compiler schedules at VGPR=44).
// Grid 576 = 72 x 8n; block = 4 waves; wave = (g, 64-site tile).
// offs_part[8][N][18][HW] partials. XCD-pinned by n.
// ---------------------------------------------------------------------------
__global__ __launch_bounds__(256, 2) void offset_conv_mfma(
    const unsigned short* __restrict__ qsT,
    const unsigned short* __restrict__ Wm3, float* __restrict__ offs_part) {
  const int bid = blockIdx.x;
  const int n    = bid & 7;            // XCD pin
  const int rest = bid >> 3;           // 0..71
  const int tid = threadIdx.x;
  const int w = tid >> 6;
  const int wi = rest * 4 + w;         // 0..287
  const int st = wi % 36;              // 64-site tile
  const int g  = wi / 36;              // 0..7 (64 ch each)
  const int l = tid & 63;
  const int lane31 = l & 31;
  const int half = l >> 5;

  const int s0 = st * 64 + lane31;
  const int s1 = s0 + 32;
  const int ps0 = (s0 / 48) * 52 + (s0 % 48);   // unpadded corner in padded plane
  const int ps1 = (s1 / 48) * 52 + (s1 % 48);

  const unsigned short* qn = qsT + (size_t)n * NCG * PPL * 8;

  f32x16 acc0 = {0.f, 0.f, 0.f, 0.f, 0.f, 0.f, 0.f, 0.f,
                 0.f, 0.f, 0.f, 0.f, 0.f, 0.f, 0.f, 0.f};
  f32x16 acc1 = acc0;

#pragma unroll
  for (int kk = 0; kk < 4; ++kk) {
    const int cg = g * 8 + kk * 2 + half;
    const unsigned short* bb0 = qn + ((size_t)cg * PPL + ps0) * 8;
    const unsigned short* bb1 = qn + ((size_t)cg * PPL + ps1) * 8;
    const unsigned short* aa  =
        Wm3 + ((size_t)((g * 4 + kk) * 2 + half) * 32 + lane31) * 200;

    short8 abuf[2][5], b0buf[2][5], b1buf[2][5];

    // prologue: taps 0..4 into buffer 0
#pragma unroll
    for (int i = 0; i < 5; ++i) {
      const int off = i * 8;                       // row 0, cols 0..4
      abuf[0][i]  = *(const short8*)(aa + i * 8);
      b0buf[0][i] = *(const short8*)(bb0 + off);
      b1buf[0][i] = *(const short8*)(bb1 + off);
    }

#pragma unroll
    for (int tg = 0; tg < 5; ++tg) {
      if (tg < 4) {
        // issue next group's 15 loads before this group's MFMAs
#pragma unroll
        for (int i = 0; i < 5; ++i) {
          const int t = (tg + 1) * 5 + i;
          const int off = ((t / 5) * 52 + (t % 5)) * 8;   // compile-time
          abuf[(tg + 1) & 1][i]  = *(const short8*)(aa + t * 8);
          b0buf[(tg + 1) & 1][i] = *(const short8*)(bb0 + off);
          b1buf[(tg + 1) & 1][i] = *(const short8*)(bb1 + off);
        }
      }
#pragma unroll
      for (int i = 0; i < 5; ++i) {
        acc0 = __builtin_amdgcn_mfma_f32_32x32x16_bf16(abuf[tg & 1][i], b0buf[tg & 1][i], acc0, 0, 0, 0);
        acc1 = __builtin_amdgcn_mfma_f32_32x32x16_bf16(abuf[tg & 1][i], b1buf[tg & 1][i], acc1, 0, 0, 0);
      }
    }
  }

  float* dst = offs_part + ((size_t)(g * NN + n) * OCONV) * HW;
#pragma unroll
  for (int r = 0; r < 16; ++r) {
    const int o = (r & 3) + 8 * (r >> 2) + 4 * half;
    if (o < OCONV) {
      dst[(size_t)o * HW + s0] = acc0[r];
      dst[(size_t)o * HW + s1] = acc1[r];
    }
  }
}

// ---------------------------------------------------------------------------
// Kernel 3: fold split-K partials + precompute bilinear params.
// par[n][k][p][8]: {w00,w01,w10,w11 (f32), a00,a01,a10,a11 (int)}. XCD-pinned.
// ---------------------------------------------------------------------------
__global__ __launch_bounds__(256) void param_kernel(
    const float* __restrict__ offs_part, float* __restrict__ par) {
  const int n  = blockIdx.x & 7;       // XCD pin
  const int j  = blockIdx.x >> 3;      // 0..80
  const int il = j * 256 + threadIdx.x;
  const int p = il % HW;
  const int k = il / HW;
  const int y = p / WW, x = p % WW;

  float dy = 0.f, dx = 0.f;
#pragma unroll
  for (int g = 0; g < G1; ++g) {
    const float* base = offs_part + ((size_t)(g * NN + n) * OCONV + 2 * k) * HW + p;
    dy += base[0];
    dx += base[HW];
  }
  const float sy = (float)(y + k / 3 - 1) + dy;
  const float sx = (float)(x + k % 3 - 1) + dx;
  const float y0 = floorf(sy), x0 = floorf(sx);
  const float ly = sy - y0,  lx = sx - x0;
  const float y1 = y0 + 1.f, x1 = x0 + 1.f;
  const float vy0 = (y0 >= 0.f && y0 <= (float)(HH - 1)) ? 1.f : 0.f;
  const float vy1 = (y1 >= 0.f && y1 <= (float)(HH - 1)) ? 1.f : 0.f;
  const float vx0 = (x0 >= 0.f && x0 <= (float)(WW - 1)) ? 1.f : 0.f;
  const float vx1 = (x1 >= 0.f && x1 <= (float)(WW - 1)) ? 1.f : 0.f;
  const int yi0 = min(max((int)y0, 0), HH - 1);
  const int yi1 = min(max((int)y1, 0), HH - 1);
  const int xi0 = min(max((int)x0, 0), WW - 1);
  const int xi1 = min(max((int)x1, 0), WW - 1);

  float* d = par + ((size_t)n * KTAP * HW + il) * 8;
  d[0] = (1.f - ly) * (1.f - lx) * vy0 * vx0;
  d[1] = (1.f - ly) * lx * vy0 * vx1;
  d[2] = ly * (1.f - lx) * vy1 * vx0;
  d[3] = ly * lx * vy1 * vx1;
  int* di = (int*)d;
  di[4] = yi0 * WW + xi0;
  di[5] = yi0 * WW + xi1;
  di[6] = yi1 * WW + xi0;
  di[7] = yi1 * WW + xi1;
}

// ---------------------------------------------------------------------------
// Kernel 4: D[n][m][site] = sum_c wk[o][c][k] * sup[n][c][site], m=k*9+o.
// B = support cg-planes (32..63), padded site addressing. XCD-pinned.
// ---------------------------------------------------------------------------
__global__ __launch_bounds__(256) void deform_gemm(
    const unsigned short* __restrict__ qsT, const unsigned short* __restrict__ wkm,
    float* __restrict__ D) {
  const int bid = blockIdx.x;
  const int n    = bid & 7;           // XCD pin
  const int rest = bid >> 3;          // 0..53
  const int tid = threadIdx.x;
  const int w = tid >> 6;
  const int wid = rest * 4 + w;       // 0..215
  const int st = wid % 72;            // site tile
  const int mt = wid / 72;            // m tile 0..2
  const int l = tid & 63;
  const int lane31 = l & 31;
  const int half = l >> 5;
  const int s = st * 32 + lane31;
  const int psite = (s / 48) * 52 + (s % 48) + 2 * 52 + 2;

  const unsigned short* qn = qsT + (size_t)n * NCG * PPL * 8;
  const unsigned short* asrc = wkm + (size_t)(half * 32 + lane31) * 8;

  f32x16 acc = {0.f, 0.f, 0.f, 0.f, 0.f, 0.f, 0.f, 0.f,
                0.f, 0.f, 0.f, 0.f, 0.f, 0.f, 0.f, 0.f};

#pragma unroll
  for (int cb = 0; cb < 16; ++cb) {
    const int cg = 32 + cb * 2 + half;
    const short8 b = *(const short8*)(qn + ((size_t)cg * PPL + psite) * 8);
    const short8 a = *(const short8*)(asrc + (size_t)((mt * 16 + cb) * 2) * 256);
    acc = __builtin_amdgcn_mfma_f32_32x32x16_bf16(a, b, acc, 0, 0, 0);
  }

  float* Dn = D + (size_t)n * MM * HW;
#pragma unroll
  for (int r = 0; r < 16; ++r) {
    const int m = mt * 32 + (r & 3) + 8 * (r >> 2) + 4 * half;
    Dn[(size_t)m * HW + s] = acc[r];
  }
}

// ---------------------------------------------------------------------------
// Kernel 5: combine + sigmoid. One thread per output element. XCD-pinned.
// ---------------------------------------------------------------------------
__global__ __launch_bounds__(256) void deform_combine(
    const float* __restrict__ D, const float* __restrict__ par,
    float* __restrict__ out) {
  const int bid = blockIdx.x;          // 648 = 81 * 8n
  const int n  = bid & 7;              // XCD pin
  const int rr = bid >> 3;             // 0..80
  const int o  = rr / 9;
  const int p  = (rr % 9) * 256 + threadIdx.x;

  const float* Dn = D + (size_t)n * MM * HW;
  const float* pb = par + ((size_t)n * KTAP * HW + p) * 8;

  float s = 0.f;
#pragma unroll
  for (int k = 0; k < KTAP; ++k) {
    const float4 wv = *(const float4*)(pb + (size_t)k * HW * 8);
    const int4  av = *(const int4*)(pb + (size_t)k * HW * 8 + 4);
    const float* base = Dn + (size_t)(k * 9 + o) * HW;
    s += wv.x * base[av.x] + wv.y * base[av.y] +
         wv.z * base[av.z] + wv.w * base[av.w];
  }
  out[((size_t)n * KTAP + o) * HW + p] = 1.f / (1.f + __expf(-s));
}

extern "C" void kernel_launch(void* const* d_in, const int* in_sizes, int n_in,
                              void* d_out, int out_size, void* d_ws, size_t ws_size,
                              hipStream_t stream) {
  const float* support  = (const float*)d_in[0];
  const float* query    = (const float*)d_in[1];
  const float* w_off    = (const float*)d_in[2];
  const float* w_kernel = (const float*)d_in[3];
  float* out = (float*)d_out;

  // ws layout (float units), ~39 MB:
  // [qsT 22.2MB][par 5.3MB][Wm3 0.82MB][wkm 0.1MB][X: offs_part 10.6MB / D 7.1MB]
  float* base = (float*)d_ws;
  unsigned short* qsT = (unsigned short*)base;                  // 8*64*PPL*8 bf16
  float* par = base + (size_t)NN * NCG * PPL * 8 / 2;           // NN*9*HW*8 f
  float* tail = par + (size_t)NN * KTAP * HW * 8;
  unsigned short* Wm3 = (unsigned short*)tail;                  // 409600 bf16 = 204800 f
  unsigned short* wkm = (unsigned short*)(tail + 204800);       // 49152 bf16 = 24576 f
  float* X = tail + 204800 + 24576;
  float* offs_part = X;                                         // G1*NSZ f (early)
  float* D = X;                                                 // NN*MM*HW f (late, aliases)

  prep_weights<<<1696, 256, 0, stream>>>(w_off, w_kernel, Wm3, wkm);
  transpose_kernel<<<8 * 72 * 16, 256, 0, stream>>>(support, query, qsT);
  offset_conv_mfma<<<72 * 8, 256, 0, stream>>>(qsT, Wm3, offs_part);
  param_kernel<<<81 * 8, 256, 0, stream>>>(offs_part, par);
  deform_gemm<<<54 * 8, 256, 0, stream>>>(qsT, wkm, D);   // D aliases offs_part (dead)
  deform_combine<<<81 * 8, 256, 0, stream>>>(D, par, out);
}

// Round 14
// 63.375 us; speedup vs baseline: 1.3464x; 1.3464x over previous
//
#include <hip/hip_runtime.h>
#include <math.h>

#define NN 8
#define CC 256        // channels per tensor (concat input has 2*CC = 512)
#define HH 48
#define WW 48
#define HW 2304       // 48*48
#define OCONV 18      // offset-conv output channels (2*K)
#define KTAP 9        // deform taps
#define G1 8          // split-K groups for offset conv (512/8 = 64 ch/group)
#define NSZ (NN * OCONV * HW)   // 331776
#define MM 96         // padded deform-GEMM rows (81 used)
#define NCG 64        // 512 ch / 8
#define PPL 2704      // padded plane sites: 52*52 (2-site zero border)

typedef __attribute__((ext_vector_type(8))) short short8;   // 8 bf16 (4 VGPRs)
typedef __attribute__((ext_vector_type(16))) float f32x16;  // 32x32 MFMA acc

static __device__ __forceinline__ unsigned short f2bf(float f) {
  unsigned u = __float_as_uint(f);
  unsigned r = (u + 0x7fffu + ((u >> 16) & 1u)) >> 16;   // round-to-nearest-even
  return (unsigned short)r;
}

// ---------------------------------------------------------------------------
// Kernel 0: weight prep (merged).
// Blocks 0..1599: Wm[t][cb(64)][o(32)][j(8)] bf16 A-frags (R3-proven layout);
//   c = cb*8+j. A-frag load for (t, cb): 1KB contiguous per wave.
// Blocks 1600..1695: wkm A-frags (rows m=k*9+o, pad 96).
// ---------------------------------------------------------------------------
__global__ __launch_bounds__(256) void prep_weights(
    const float* __restrict__ w_off, const float* __restrict__ w_kernel,
    unsigned short* __restrict__ Wm, unsigned short* __restrict__ wkm) {
  const int b = blockIdx.x;
  if (b < 1600) {
    const int i = b * 256 + threadIdx.x;      // < 409600
    const int j  = i & 7;
    const int o  = (i >> 3) & 31;
    const int cb = (i >> 8) & 63;
    const int t  = i >> 14;
    float v = 0.f;
    if (o < OCONV) v = w_off[(size_t)(o * (2 * CC) + cb * 8 + j) * 25 + t];
    Wm[i] = f2bf(v);
  } else {
    const int i = (b - 1600) * 256 + threadIdx.x;
    if (i >= 3 * 16 * 2 * 32 * 8) return;
    const int j    = i & 7;
    const int r    = (i >> 3) & 31;
    const int half = (i >> 8) & 1;
    const int cb   = (i >> 9) & 15;
    const int mt   = i >> 13;
    const int m = mt * 32 + r;
    const int c = cb * 16 + half * 8 + j;
    float v = 0.f;
    if (m < 81) {
      const int k = m / 9, o = m % 9;
      v = w_kernel[(size_t)(o * CC + c) * KTAP + k];
    }
    wkm[i] = f2bf(v);
  }
}

// ---------------------------------------------------------------------------
// Kernel 1: transpose query+support -> qsT[n][cg][52x52 padded][8ch] bf16.
// Interior site (y,x) -> padded (y+2)*52+(x+2); 2-wide border zeroed by
// pt==0 blocks. XCD-pinned by n.
// ---------------------------------------------------------------------------
__global__ __launch_bounds__(256) void transpose_kernel(
    const float* __restrict__ support, const float* __restrict__ query,
    unsigned short* __restrict__ qsT) {
  const int bid = blockIdx.x;         // 9216 = 8n * 72pt * 16ct
  const int n    = bid & 7;           // XCD pin
  const int rest = bid >> 3;
  const int pt = rest % 72;
  const int ct = rest / 72;           // 0..15; 32-ch block
  const int p0 = pt * 32;
  const int tid = threadIdx.x;

  __shared__ float tile[32][33];

  const float* plane = ((ct < 8) ? query : support) +
                       ((size_t)n * CC + (ct & 7) * 32) * HW;
#pragma unroll
  for (int j = 0; j < 4; ++j) {
    const int idx = tid + j * 256;
    const int cc = idx >> 5, pp = idx & 31;
    tile[pp][cc] = plane[(size_t)cc * HW + p0 + pp];
  }
  __syncthreads();

  unsigned short* qn = qsT + (size_t)n * NCG * PPL * 8;
  const int cgbase = ((ct < 8) ? 0 : 32) + (ct & 7) * 4;

  if (tid < 128) {
    const int pp  = tid & 31;
    const int cgl = tid >> 5;          // 0..3
    const int s = p0 + pp;
    const int y = s / 48, x = s % 48;
    const int psite = (y + 2) * 52 + (x + 2);
    const float* row = &tile[pp][cgl * 8];
    uint4 w;
    w.x = (unsigned)f2bf(row[0]) | ((unsigned)f2bf(row[1]) << 16);
    w.y = (unsigned)f2bf(row[2]) | ((unsigned)f2bf(row[3]) << 16);
    w.z = (unsigned)f2bf(row[4]) | ((unsigned)f2bf(row[5]) << 16);
    w.w = (unsigned)f2bf(row[6]) | ((unsigned)f2bf(row[7]) << 16);
    *(uint4*)(qn + ((size_t)(cgbase + cgl) * PPL + psite) * 8) = w;
  }

  // zero border: 400 border sites x 4 cg planes, done by pt==0 blocks
  if (pt == 0) {
    const uint4 zz = make_uint4(0u, 0u, 0u, 0u);
    for (int z = tid; z < 1600; z += 256) {
      const int cgl = z / 400;
      const int e   = z % 400;
      int row, col;
      if (e < 104)      { row = e / 52;              col = e % 52; }          // rows 0,1
      else if (e < 208) { row = 50 + (e - 104) / 52; col = (e - 104) % 52; }  // rows 50,51
      else {
        const int f = e - 208;                                               // cols 0,1,50,51
        row = 2 + f / 4;
        const int cs = f % 4;
        col = (cs < 2) ? cs : (48 + cs);
      }
      *(uint4*)(qn + ((size_t)(cgbase + cgl) * PPL + row * 52 + col) * 8) = zz;
    }
  }
}

// ---------------------------------------------------------------------------
// Kernel 2: offset conv, LDS-staged implicit GEMM.
// Block = 384 thr (6 waves) = (n, g, 4-row tile). Stage 8 cg x 8 padded rows
// x 52 x 16B = 53KB to LDS (vector reg-staging); compute reads are
// ds_read_b128 at compile-time immediates (no VALU addr, conflict-free).
// A: 4-deep register ring, batch loads pinned with sched_barrier(0) so the
// scheduler cannot collapse the pipeline (R13 failure mode).
// offs_part[8][N][18][HW] partials. XCD-pinned by n.
// ---------------------------------------------------------------------------
__global__ __launch_bounds__(384, 3) void offset_conv_mfma(
    const unsigned short* __restrict__ qsT,
    const unsigned short* __restrict__ Wm, float* __restrict__ offs_part) {
  const int bid = blockIdx.x;        // 768 = 12rt * 8g * 8n
  const int n  = bid & 7;            // XCD pin
  const int r2 = bid >> 3;           // 0..95
  const int g  = r2 & 7;             // channel group (64 ch)
  const int rt = r2 >> 3;            // 0..11 (4 image rows each)
  const int tid = threadIdx.x;

  __shared__ __align__(16) unsigned short lds[3328 * 8];   // 53,248 B

  // ---- stage: cg 0..7 (abs g*8+cg), padded rows rt*4..rt*4+7, cols 0..51 ----
  const unsigned short* qn = qsT + ((size_t)n * NCG + g * 8) * PPL * 8;
  for (int c = tid; c < 3328; c += 384) {
    const int cg  = c / 416;
    const int rem = c - cg * 416;                    // rr*52 + col
    const uint4 v = *(const uint4*)(qn + ((size_t)cg * PPL + rt * 4 * 52 + rem) * 8);
    *(uint4*)(lds + (size_t)c * 8) = v;
  }
  __syncthreads();

  const int w = tid >> 6;            // wave 0..5
  const int l = tid & 63;
  const int l31 = l & 31;
  const int half = l >> 5;
  const int si = w * 32 + l31;       // 0..191 within row tile
  const int rr0 = si / 48;           // 0..3
  const int x   = si % 48;

  const unsigned short* lbase = lds + (half * 416 + rr0 * 52 + x) * 8;
  const unsigned short* abase = Wm + (size_t)((g * 8 + half) * 32 + l31) * 8;
  // A(t,kk) = abase + t*16384 + kk*512 (shorts)

  f32x16 acc = {0.f, 0.f, 0.f, 0.f, 0.f, 0.f, 0.f, 0.f,
                0.f, 0.f, 0.f, 0.f, 0.f, 0.f, 0.f, 0.f};

  short8 a[4][4];                    // [t mod 4][kk] ring
#pragma unroll
  for (int t = 0; t < 4; ++t)
#pragma unroll
    for (int kk = 0; kk < 4; ++kk)
      a[t][kk] = *(const short8*)(abase + t * 16384 + kk * 512);

#pragma unroll
  for (int t = 0; t < 25; ++t) {
    const int u = t / 5, v5 = t % 5;
    const int loff = (u * 52 + v5) * 8;              // compile-time (shorts)
#pragma unroll
    for (int kk = 0; kk < 4; ++kk) {
      const short8 b = *(const short8*)(lbase + kk * 6656 + loff);
      acc = __builtin_amdgcn_mfma_f32_32x32x16_bf16(a[t & 3][kk], b, acc, 0, 0, 0);
    }
    if (t < 21) {
#pragma unroll
      for (int kk = 0; kk < 4; ++kk)
        a[t & 3][kk] = *(const short8*)(abase + (t + 4) * 16384 + kk * 512);
    }
    __builtin_amdgcn_sched_barrier(0);
  }

  float* dst = offs_part + ((size_t)(g * NN + n) * OCONV) * HW;
  const int s0 = rt * 192 + si;
#pragma unroll
  for (int r = 0; r < 16; ++r) {
    const int o = (r & 3) + 8 * (r >> 2) + 4 * half;
    if (o < OCONV) dst[(size_t)o * HW + s0] = acc[r];
  }
}

// ---------------------------------------------------------------------------
// Kernel 3: fold split-K partials + precompute bilinear params.
// par[n][k][p][8]: {w00,w01,w10,w11 (f32), a00,a01,a10,a11 (int)}. XCD-pinned.
// ---------------------------------------------------------------------------
__global__ __launch_bounds__(256) void param_kernel(
    const float* __restrict__ offs_part, float* __restrict__ par) {
  const int n  = blockIdx.x & 7;       // XCD pin
  const int j  = blockIdx.x >> 3;      // 0..80
  const int il = j * 256 + threadIdx.x;
  const int p = il % HW;
  const int k = il / HW;
  const int y = p / WW, x = p % WW;

  float dy = 0.f, dx = 0.f;
#pragma unroll
  for (int g = 0; g < G1; ++g) {
    const float* base = offs_part + ((size_t)(g * NN + n) * OCONV + 2 * k) * HW + p;
    dy += base[0];
    dx += base[HW];
  }
  const float sy = (float)(y + k / 3 - 1) + dy;
  const float sx = (float)(x + k % 3 - 1) + dx;
  const float y0 = floorf(sy), x0 = floorf(sx);
  const float ly = sy - y0,  lx = sx - x0;
  const float y1 = y0 + 1.f, x1 = x0 + 1.f;
  const float vy0 = (y0 >= 0.f && y0 <= (float)(HH - 1)) ? 1.f : 0.f;
  const float vy1 = (y1 >= 0.f && y1 <= (float)(HH - 1)) ? 1.f : 0.f;
  const float vx0 = (x0 >= 0.f && x0 <= (float)(WW - 1)) ? 1.f : 0.f;
  const float vx1 = (x1 >= 0.f && x1 <= (float)(WW - 1)) ? 1.f : 0.f;
  const int yi0 = min(max((int)y0, 0), HH - 1);
  const int yi1 = min(max((int)y1, 0), HH - 1);
  const int xi0 = min(max((int)x0, 0), WW - 1);
  const int xi1 = min(max((int)x1, 0), WW - 1);

  float* d = par + ((size_t)n * KTAP * HW + il) * 8;
  d[0] = (1.f - ly) * (1.f - lx) * vy0 * vx0;
  d[1] = (1.f - ly) * lx * vy0 * vx1;
  d[2] = ly * (1.f - lx) * vy1 * vx0;
  d[3] = ly * lx * vy1 * vx1;
  int* di = (int*)d;
  di[4] = yi0 * WW + xi0;
  di[5] = yi0 * WW + xi1;
  di[6] = yi1 * WW + xi0;
  di[7] = yi1 * WW + xi1;
}

// ---------------------------------------------------------------------------
// Kernel 4: D[n][m][site] = sum_c wk[o][c][k] * sup[n][c][site], m=k*9+o.
// B = support cg-planes (32..63), padded site addressing. XCD-pinned.
// ---------------------------------------------------------------------------
__global__ __launch_bounds__(256) void deform_gemm(
    const unsigned short* __restrict__ qsT, const unsigned short* __restrict__ wkm,
    float* __restrict__ D) {
  const int bid = blockIdx.x;
  const int n    = bid & 7;           // XCD pin
  const int rest = bid >> 3;          // 0..53
  const int tid = threadIdx.x;
  const int w = tid >> 6;
  const int wid = rest * 4 + w;       // 0..215
  const int st = wid % 72;            // site tile
  const int mt = wid / 72;            // m tile 0..2
  const int l = tid & 63;
  const int lane31 = l & 31;
  const int half = l >> 5;
  const int s = st * 32 + lane31;
  const int psite = (s / 48) * 52 + (s % 48) + 2 * 52 + 2;

  const unsigned short* qn = qsT + (size_t)n * NCG * PPL * 8;
  const unsigned short* asrc = wkm + (size_t)(half * 32 + lane31) * 8;

  f32x16 acc = {0.f, 0.f, 0.f, 0.f, 0.f, 0.f, 0.f, 0.f,
                0.f, 0.f, 0.f, 0.f, 0.f, 0.f, 0.f, 0.f};

#pragma unroll
  for (int cb = 0; cb < 16; ++cb) {
    const int cg = 32 + cb * 2 + half;
    const short8 b = *(const short8*)(qn + ((size_t)cg * PPL + psite) * 8);
    const short8 a = *(const short8*)(asrc + (size_t)((mt * 16 + cb) * 2) * 256);
    acc = __builtin_amdgcn_mfma_f32_32x32x16_bf16(a, b, acc, 0, 0, 0);
  }

  float* Dn = D + (size_t)n * MM * HW;
#pragma unroll
  for (int r = 0; r < 16; ++r) {
    const int m = mt * 32 + (r & 3) + 8 * (r >> 2) + 4 * half;
    Dn[(size_t)m * HW + s] = acc[r];
  }
}

// ---------------------------------------------------------------------------
// Kernel 5: combine + sigmoid. One thread per output element. XCD-pinned.
// ---------------------------------------------------------------------------
__global__ __launch_bounds__(256) void deform_combine(
    const float* __restrict__ D, const float* __restrict__ par,
    float* __restrict__ out) {
  const int bid = blockIdx.x;          // 648 = 81 * 8n
  const int n  = bid & 7;              // XCD pin
  const int rr = bid >> 3;             // 0..80
  const int o  = rr / 9;
  const int p  = (rr % 9) * 256 + threadIdx.x;

  const float* Dn = D + (size_t)n * MM * HW;
  const float* pb = par + ((size_t)n * KTAP * HW + p) * 8;

  float s = 0.f;
#pragma unroll
  for (int k = 0; k < KTAP; ++k) {
    const float4 wv = *(const float4*)(pb + (size_t)k * HW * 8);
    const int4  av = *(const int4*)(pb + (size_t)k * HW * 8 + 4);
    const float* base = Dn + (size_t)(k * 9 + o) * HW;
    s += wv.x * base[av.x] + wv.y * base[av.y] +
         wv.z * base[av.z] + wv.w * base[av.w];
  }
  out[((size_t)n * KTAP + o) * HW + p] = 1.f / (1.f + __expf(-s));
}

extern "C" void kernel_launch(void* const* d_in, const int* in_sizes, int n_in,
                              void* d_out, int out_size, void* d_ws, size_t ws_size,
                              hipStream_t stream) {
  const float* support  = (const float*)d_in[0];
  const float* query    = (const float*)d_in[1];
  const float* w_off    = (const float*)d_in[2];
  const float* w_kernel = (const float*)d_in[3];
  float* out = (float*)d_out;

  // ws layout (float units), ~39 MB:
  // [qsT 22.2MB][par 5.3MB][Wm 0.82MB][wkm 0.1MB][X: offs_part 10.6MB / D 7.1MB]
  float* base = (float*)d_ws;
  unsigned short* qsT = (unsigned short*)base;                  // 8*64*PPL*8 bf16
  float* par = base + (size_t)NN * NCG * PPL * 8 / 2;           // NN*9*HW*8 f
  float* tail = par + (size_t)NN * KTAP * HW * 8;
  unsigned short* Wm  = (unsigned short*)tail;                  // 409600 bf16 = 204800 f
  unsigned short* wkm = (unsigned short*)(tail + 204800);       // 49152 bf16 = 24576 f
  float* X = tail + 204800 + 24576;
  float* offs_part = X;                                         // G1*NSZ f (early)
  float* D = X;                                                 // NN*MM*HW f (late, aliases)

  prep_weights<<<1696, 256, 0, stream>>>(w_off, w_kernel, Wm, wkm);
  transpose_kernel<<<8 * 72 * 16, 256, 0, stream>>>(support, query, qsT);
  offset_conv_mfma<<<768, 384, 0, stream>>>(qsT, Wm, offs_part);
  param_kernel<<<81 * 8, 256, 0, stream>>>(offs_part, par);
  deform_gemm<<<54 * 8, 256, 0, stream>>>(qsT, wkm, D);   // D aliases offs_part (dead)
  deform_combine<<<81 * 8, 256, 0, stream>>>(D, par, out);
}

// Round 15
// 62.590 us; speedup vs baseline: 1.3633x; 1.0125x over previous
//
#include <hip/hip_runtime.h>
#include <math.h>

#define NN 8
#define CC 256        // channels per tensor (concat input has 2*CC = 512)
#define HH 48
#define WW 48
#define HW 2304       // 48*48
#define OCONV 18      // offset-conv output channels (2*K)
#define KTAP 9        // deform taps
#define G1 8          // split-K groups for offset conv (512/8 = 64 ch/group)
#define NSZ (NN * OCONV * HW)   // 331776
#define MM 96         // padded deform-GEMM rows (81 used)
#define NCG 64        // 512 ch / 8
#define PPL 2704      // padded plane sites: 52*52 (2-site zero border)

typedef __attribute__((ext_vector_type(8))) short short8;   // 8 bf16 (4 VGPRs)
typedef __attribute__((ext_vector_type(16))) float f32x16;  // 32x32 MFMA acc

static __device__ __forceinline__ unsigned short f2bf(float f) {
  unsigned u = __float_as_uint(f);
  unsigned r = (u + 0x7fffu + ((u >> 16) & 1u)) >> 16;   // round-to-nearest-even
  return (unsigned short)r;
}

// ---------------------------------------------------------------------------
// Kernel 0: weight prep (merged).
// Blocks 0..1599: Wm[t][cb(64)][o(32)][j(8)] bf16 A-frags; c = cb*8+j.
// Blocks 1600..1695: wkm A-frags (rows m=k*9+o, pad 96).
// ---------------------------------------------------------------------------
__global__ __launch_bounds__(256) void prep_weights(
    const float* __restrict__ w_off, const float* __restrict__ w_kernel,
    unsigned short* __restrict__ Wm, unsigned short* __restrict__ wkm) {
  const int b = blockIdx.x;
  if (b < 1600) {
    const int i = b * 256 + threadIdx.x;      // < 409600
    const int j  = i & 7;
    const int o  = (i >> 3) & 31;
    const int cb = (i >> 8) & 63;
    const int t  = i >> 14;
    float v = 0.f;
    if (o < OCONV) v = w_off[(size_t)(o * (2 * CC) + cb * 8 + j) * 25 + t];
    Wm[i] = f2bf(v);
  } else {
    const int i = (b - 1600) * 256 + threadIdx.x;
    if (i >= 3 * 16 * 2 * 32 * 8) return;
    const int j    = i & 7;
    const int r    = (i >> 3) & 31;
    const int half = (i >> 8) & 1;
    const int cb   = (i >> 9) & 15;
    const int mt   = i >> 13;
    const int m = mt * 32 + r;
    const int c = cb * 16 + half * 8 + j;
    float v = 0.f;
    if (m < 81) {
      const int k = m / 9, o = m % 9;
      v = w_kernel[(size_t)(o * CC + c) * KTAP + k];
    }
    wkm[i] = f2bf(v);
  }
}

// ---------------------------------------------------------------------------
// Kernel 1: transpose query+support -> qsT[n][cg][52x52 padded][8ch] bf16.
// Interior site (y,x) -> padded (y+2)*52+(x+2); 2-wide border zeroed by
// pt==0 blocks. XCD-pinned by n.
// ---------------------------------------------------------------------------
__global__ __launch_bounds__(256) void transpose_kernel(
    const float* __restrict__ support, const float* __restrict__ query,
    unsigned short* __restrict__ qsT) {
  const int bid = blockIdx.x;         // 9216 = 8n * 72pt * 16ct
  const int n    = bid & 7;           // XCD pin
  const int rest = bid >> 3;
  const int pt = rest % 72;
  const int ct = rest / 72;           // 0..15; 32-ch block
  const int p0 = pt * 32;
  const int tid = threadIdx.x;

  __shared__ float tile[32][33];

  const float* plane = ((ct < 8) ? query : support) +
                       ((size_t)n * CC + (ct & 7) * 32) * HW;
#pragma unroll
  for (int j = 0; j < 4; ++j) {
    const int idx = tid + j * 256;
    const int cc = idx >> 5, pp = idx & 31;
    tile[pp][cc] = plane[(size_t)cc * HW + p0 + pp];
  }
  __syncthreads();

  unsigned short* qn = qsT + (size_t)n * NCG * PPL * 8;
  const int cgbase = ((ct < 8) ? 0 : 32) + (ct & 7) * 4;

  if (tid < 128) {
    const int pp  = tid & 31;
    const int cgl = tid >> 5;          // 0..3
    const int s = p0 + pp;
    const int y = s / 48, x = s % 48;
    const int psite = (y + 2) * 52 + (x + 2);
    const float* row = &tile[pp][cgl * 8];
    uint4 w;
    w.x = (unsigned)f2bf(row[0]) | ((unsigned)f2bf(row[1]) << 16);
    w.y = (unsigned)f2bf(row[2]) | ((unsigned)f2bf(row[3]) << 16);
    w.z = (unsigned)f2bf(row[4]) | ((unsigned)f2bf(row[5]) << 16);
    w.w = (unsigned)f2bf(row[6]) | ((unsigned)f2bf(row[7]) << 16);
    *(uint4*)(qn + ((size_t)(cgbase + cgl) * PPL + psite) * 8) = w;
  }

  // zero border: 400 border sites x 4 cg planes, done by pt==0 blocks
  if (pt == 0) {
    const uint4 zz = make_uint4(0u, 0u, 0u, 0u);
    for (int z = tid; z < 1600; z += 256) {
      const int cgl = z / 400;
      const int e   = z % 400;
      int row, col;
      if (e < 104)      { row = e / 52;              col = e % 52; }          // rows 0,1
      else if (e < 208) { row = 50 + (e - 104) / 52; col = (e - 104) % 52; }  // rows 50,51
      else {
        const int f = e - 208;                                               // cols 0,1,50,51
        row = 2 + f / 4;
        const int cs = f % 4;
        col = (cs < 2) ? cs : (48 + cs);
      }
      *(uint4*)(qn + ((size_t)(cgbase + cgl) * PPL + row * 52 + col) * 8) = zz;
    }
  }
}

// ---------------------------------------------------------------------------
// Kernel 2: offset conv, LDS-staged implicit GEMM, 64 sites/wave (2 acc).
// Block = 192 thr (3 waves) = (n, g, 4-row tile). Stage 8 cg x 8 padded rows
// x 52 x 16B = 53KB to LDS; compute reads are ds_read_b128 at compile-time
// immediates. Each A-fragment feeds TWO MFMAs (2 site-tiles) -> A-L2 traffic
// halved vs 32-site waves. A-ring + sched_barrier pins the prefetch pipeline
// (R13: scheduler dissolves it otherwise). Grid 768 = exactly 3 blocks/CU.
// offs_part[8][N][18][HW] partials. XCD-pinned by n.
// ---------------------------------------------------------------------------
__global__ __launch_bounds__(192, 2) void offset_conv_mfma(
    const unsigned short* __restrict__ qsT,
    const unsigned short* __restrict__ Wm, float* __restrict__ offs_part) {
  const int bid = blockIdx.x;        // 768 = 12rt * 8g * 8n
  const int n  = bid & 7;            // XCD pin
  const int r2 = bid >> 3;           // 0..95
  const int g  = r2 & 7;             // channel group (64 ch)
  const int rt = r2 >> 3;            // 0..11 (4 image rows each)
  const int tid = threadIdx.x;

  __shared__ __align__(16) unsigned short lds[3328 * 8];   // 53,248 B

  // ---- stage: cg 0..7 (abs g*8+cg), padded rows rt*4..rt*4+7, cols 0..51 ----
  const unsigned short* qn = qsT + ((size_t)n * NCG + g * 8) * PPL * 8;
  for (int c = tid; c < 3328; c += 192) {
    const int cg  = c / 416;
    const int rem = c - cg * 416;                    // rr*52 + col
    const uint4 v = *(const uint4*)(qn + ((size_t)cg * PPL + rt * 4 * 52 + rem) * 8);
    *(uint4*)(lds + (size_t)c * 8) = v;
  }
  __syncthreads();

  const int w = tid >> 6;            // wave 0..2
  const int l = tid & 63;
  const int l31 = l & 31;
  const int half = l >> 5;
  const int si0 = w * 64 + l31;      // first site (0..191 within row tile)
  const int si1 = si0 + 32;          // second site
  const int rrA = si0 / 48, xA = si0 % 48;
  const int rrB = si1 / 48, xB = si1 % 48;

  const unsigned short* lbase0 = lds + (half * 416 + rrA * 52 + xA) * 8;
  const unsigned short* lbase1 = lds + (half * 416 + rrB * 52 + xB) * 8;
  const unsigned short* abase = Wm + (size_t)((g * 8 + half) * 32 + l31) * 8;
  // A(t,kk) = abase + t*16384 + kk*512 (shorts)

  f32x16 acc0 = {0.f, 0.f, 0.f, 0.f, 0.f, 0.f, 0.f, 0.f,
                 0.f, 0.f, 0.f, 0.f, 0.f, 0.f, 0.f, 0.f};
  f32x16 acc1 = acc0;

  short8 a[4][4];                    // [t mod 4][kk] ring
#pragma unroll
  for (int t = 0; t < 4; ++t)
#pragma unroll
    for (int kk = 0; kk < 4; ++kk)
      a[t][kk] = *(const short8*)(abase + t * 16384 + kk * 512);

#pragma unroll
  for (int t = 0; t < 25; ++t) {
    const int u = t / 5, v5 = t % 5;
    const int loff = (u * 52 + v5) * 8;              // compile-time (shorts)
#pragma unroll
    for (int kk = 0; kk < 4; ++kk) {
      const short8 b0 = *(const short8*)(lbase0 + kk * 6656 + loff);
      const short8 b1 = *(const short8*)(lbase1 + kk * 6656 + loff);
      acc0 = __builtin_amdgcn_mfma_f32_32x32x16_bf16(a[t & 3][kk], b0, acc0, 0, 0, 0);
      acc1 = __builtin_amdgcn_mfma_f32_32x32x16_bf16(a[t & 3][kk], b1, acc1, 0, 0, 0);
    }
    if (t < 21) {
#pragma unroll
      for (int kk = 0; kk < 4; ++kk)
        a[t & 3][kk] = *(const short8*)(abase + (t + 4) * 16384 + kk * 512);
    }
    __builtin_amdgcn_sched_barrier(0);
  }

  float* dst = offs_part + ((size_t)(g * NN + n) * OCONV) * HW;
  const int s0 = rt * 192 + si0;
  const int s1 = rt * 192 + si1;
#pragma unroll
  for (int r = 0; r < 16; ++r) {
    const int o = (r & 3) + 8 * (r >> 2) + 4 * half;
    if (o < OCONV) {
      dst[(size_t)o * HW + s0] = acc0[r];
      dst[(size_t)o * HW + s1] = acc1[r];
    }
  }
}

// ---------------------------------------------------------------------------
// Kernel 3: fold split-K partials + precompute bilinear params.
// par[n][k][p][8]: {w00,w01,w10,w11 (f32), a00,a01,a10,a11 (int)}. XCD-pinned.
// ---------------------------------------------------------------------------
__global__ __launch_bounds__(256) void param_kernel(
    const float* __restrict__ offs_part, float* __restrict__ par) {
  const int n  = blockIdx.x & 7;       // XCD pin
  const int j  = blockIdx.x >> 3;      // 0..80
  const int il = j * 256 + threadIdx.x;
  const int p = il % HW;
  const int k = il / HW;
  const int y = p / WW, x = p % WW;

  float dy = 0.f, dx = 0.f;
#pragma unroll
  for (int g = 0; g < G1; ++g) {
    const float* base = offs_part + ((size_t)(g * NN + n) * OCONV + 2 * k) * HW + p;
    dy += base[0];
    dx += base[HW];
  }
  const float sy = (float)(y + k / 3 - 1) + dy;
  const float sx = (float)(x + k % 3 - 1) + dx;
  const float y0 = floorf(sy), x0 = floorf(sx);
  const float ly = sy - y0,  lx = sx - x0;
  const float y1 = y0 + 1.f, x1 = x0 + 1.f;
  const float vy0 = (y0 >= 0.f && y0 <= (float)(HH - 1)) ? 1.f : 0.f;
  const float vy1 = (y1 >= 0.f && y1 <= (float)(HH - 1)) ? 1.f : 0.f;
  const float vx0 = (x0 >= 0.f && x0 <= (float)(WW - 1)) ? 1.f : 0.f;
  const float vx1 = (x1 >= 0.f && x1 <= (float)(WW - 1)) ? 1.f : 0.f;
  const int yi0 = min(max((int)y0, 0), HH - 1);
  const int yi1 = min(max((int)y1, 0), HH - 1);
  const int xi0 = min(max((int)x0, 0), WW - 1);
  const int xi1 = min(max((int)x1, 0), WW - 1);

  float* d = par + ((size_t)n * KTAP * HW + il) * 8;
  d[0] = (1.f - ly) * (1.f - lx) * vy0 * vx0;
  d[1] = (1.f - ly) * lx * vy0 * vx1;
  d[2] = ly * (1.f - lx) * vy1 * vx0;
  d[3] = ly * lx * vy1 * vx1;
  int* di = (int*)d;
  di[4] = yi0 * WW + xi0;
  di[5] = yi0 * WW + xi1;
  di[6] = yi1 * WW + xi0;
  di[7] = yi1 * WW + xi1;
}

// ---------------------------------------------------------------------------
// Kernel 4: D[n][m][site] = sum_c wk[o][c][k] * sup[n][c][site], m=k*9+o.
// B = support cg-planes (32..63), padded site addressing. XCD-pinned.
// ---------------------------------------------------------------------------
__global__ __launch_bounds__(256) void deform_gemm(
    const unsigned short* __restrict__ qsT, const unsigned short* __restrict__ wkm,
    float* __restrict__ D) {
  const int bid = blockIdx.x;
  const int n    = bid & 7;           // XCD pin
  const int rest = bid >> 3;          // 0..53
  const int tid = threadIdx.x;
  const int w = tid >> 6;
  const int wid = rest * 4 + w;       // 0..215
  const int st = wid % 72;            // site tile
  const int mt = wid / 72;            // m tile 0..2
  const int l = tid & 63;
  const int lane31 = l & 31;
  const int half = l >> 5;
  const int s = st * 32 + lane31;
  const int psite = (s / 48) * 52 + (s % 48) + 2 * 52 + 2;

  const unsigned short* qn = qsT + (size_t)n * NCG * PPL * 8;
  const unsigned short* asrc = wkm + (size_t)(half * 32 + lane31) * 8;

  f32x16 acc = {0.f, 0.f, 0.f, 0.f, 0.f, 0.f, 0.f, 0.f,
                0.f, 0.f, 0.f, 0.f, 0.f, 0.f, 0.f, 0.f};

#pragma unroll
  for (int cb = 0; cb < 16; ++cb) {
    const int cg = 32 + cb * 2 + half;
    const short8 b = *(const short8*)(qn + ((size_t)cg * PPL + psite) * 8);
    const short8 a = *(const short8*)(asrc + (size_t)((mt * 16 + cb) * 2) * 256);
    acc = __builtin_amdgcn_mfma_f32_32x32x16_bf16(a, b, acc, 0, 0, 0);
  }

  float* Dn = D + (size_t)n * MM * HW;
#pragma unroll
  for (int r = 0; r < 16; ++r) {
    const int m = mt * 32 + (r & 3) + 8 * (r >> 2) + 4 * half;
    Dn[(size_t)m * HW + s] = acc[r];
  }
}

// ---------------------------------------------------------------------------
// Kernel 5: combine + sigmoid. One thread per output element. XCD-pinned.
// ---------------------------------------------------------------------------
__global__ __launch_bounds__(256) void deform_combine(
    const float* __restrict__ D, const float* __restrict__ par,
    float* __restrict__ out) {
  const int bid = blockIdx.x;          // 648 = 81 * 8n
  const int n  = bid & 7;              // XCD pin
  const int rr = bid >> 3;             // 0..80
  const int o  = rr / 9;
  const int p  = (rr % 9) * 256 + threadIdx.x;

  const float* Dn = D + (size_t)n * MM * HW;
  const float* pb = par + ((size_t)n * KTAP * HW + p) * 8;

  float s = 0.f;
#pragma unroll
  for (int k = 0; k < KTAP; ++k) {
    const float4 wv = *(const float4*)(pb + (size_t)k * HW * 8);
    const int4  av = *(const int4*)(pb + (size_t)k * HW * 8 + 4);
    const float* base = Dn + (size_t)(k * 9 + o) * HW;
    s += wv.x * base[av.x] + wv.y * base[av.y] +
         wv.z * base[av.z] + wv.w * base[av.w];
  }
  out[((size_t)n * KTAP + o) * HW + p] = 1.f / (1.f + __expf(-s));
}

extern "C" void kernel_launch(void* const* d_in, const int* in_sizes, int n_in,
                              void* d_out, int out_size, void* d_ws, size_t ws_size,
                              hipStream_t stream) {
  const float* support  = (const float*)d_in[0];
  const float* query    = (const float*)d_in[1];
  const float* w_off    = (const float*)d_in[2];
  const float* w_kernel = (const float*)d_in[3];
  float* out = (float*)d_out;

  // ws layout (float units), ~39 MB:
  // [qsT 22.2MB][par 5.3MB][Wm 0.82MB][wkm 0.1MB][X: offs_part 10.6MB / D 7.1MB]
  float* base = (float*)d_ws;
  unsigned short* qsT = (unsigned short*)base;                  // 8*64*PPL*8 bf16
  float* par = base + (size_t)NN * NCG * PPL * 8 / 2;           // NN*9*HW*8 f
  float* tail = par + (size_t)NN * KTAP * HW * 8;
  unsigned short* Wm  = (unsigned short*)tail;                  // 409600 bf16 = 204800 f
  unsigned short* wkm = (unsigned short*)(tail + 204800);       // 49152 bf16 = 24576 f
  float* X = tail + 204800 + 24576;
  float* offs_part = X;                                         // G1*NSZ f (early)
  float* D = X;                                                 // NN*MM*HW f (late, aliases)

  prep_weights<<<1696, 256, 0, stream>>>(w_off, w_kernel, Wm, wkm);
  transpose_kernel<<<8 * 72 * 16, 256, 0, stream>>>(support, query, qsT);
  offset_conv_mfma<<<768, 192, 0, stream>>>(qsT, Wm, offs_part);
  param_kernel<<<81 * 8, 256, 0, stream>>>(offs_part, par);
  deform_gemm<<<54 * 8, 256, 0, stream>>>(qsT, wkm, D);   // D aliases offs_part (dead)
  deform_combine<<<81 * 8, 256, 0, stream>>>(D, par, out);
}

// Round 16
// 61.632 us; speedup vs baseline: 1.3845x; 1.0155x over previous
//
#include <hip/hip_runtime.h>
#include <math.h>

#define NN 8
#define CC 256        // channels per tensor (concat input has 2*CC = 512)
#define HH 48
#define WW 48
#define HW 2304       // 48*48
#define OCONV 18      // offset-conv output channels (2*K)
#define KTAP 9        // deform taps
#define G1 8          // split-K groups for offset conv (512/8 = 64 ch/group)
#define NSZ (NN * OCONV * HW)   // 331776
#define MM 96         // padded deform-GEMM rows (81 used)
#define NCG 64        // 512 ch / 8
#define PPL 2704      // padded plane sites: 52*52 (2-site zero border)

typedef __attribute__((ext_vector_type(8))) short short8;   // 8 bf16 (4 VGPRs)
typedef __attribute__((ext_vector_type(16))) float f32x16;  // 32x32 MFMA acc

static __device__ __forceinline__ unsigned short f2bf(float f) {
  unsigned u = __float_as_uint(f);
  unsigned r = (u + 0x7fffu + ((u >> 16) & 1u)) >> 16;   // round-to-nearest-even
  return (unsigned short)r;
}

// ---------------------------------------------------------------------------
// Kernel 0: weight prep (merged).
// Blocks 0..1599: Wm[t][cb(64)][o(32)][j(8)] bf16 A-frags; c = cb*8+j.
// Blocks 1600..1695: wkm A-frags (rows m=k*9+o, pad 96).
// ---------------------------------------------------------------------------
__global__ __launch_bounds__(256) void prep_weights(
    const float* __restrict__ w_off, const float* __restrict__ w_kernel,
    unsigned short* __restrict__ Wm, unsigned short* __restrict__ wkm) {
  const int b = blockIdx.x;
  if (b < 1600) {
    const int i = b * 256 + threadIdx.x;      // < 409600
    const int j  = i & 7;
    const int o  = (i >> 3) & 31;
    const int cb = (i >> 8) & 63;
    const int t  = i >> 14;
    float v = 0.f;
    if (o < OCONV) v = w_off[(size_t)(o * (2 * CC) + cb * 8 + j) * 25 + t];
    Wm[i] = f2bf(v);
  } else {
    const int i = (b - 1600) * 256 + threadIdx.x;
    if (i >= 3 * 16 * 2 * 32 * 8) return;
    const int j    = i & 7;
    const int r    = (i >> 3) & 31;
    const int half = (i >> 8) & 1;
    const int cb   = (i >> 9) & 15;
    const int mt   = i >> 13;
    const int m = mt * 32 + r;
    const int c = cb * 16 + half * 8 + j;
    float v = 0.f;
    if (m < 81) {
      const int k = m / 9, o = m % 9;
      v = w_kernel[(size_t)(o * CC + c) * KTAP + k];
    }
    wkm[i] = f2bf(v);
  }
}

// ---------------------------------------------------------------------------
// Kernel 1: transpose query+support -> qsT[n][cg][52x52 padded][8ch] bf16.
// Interior site (y,x) -> padded (y+2)*52+(x+2); 2-wide border zeroed by
// pt==0 blocks. XCD-pinned by n.
// ---------------------------------------------------------------------------
__global__ __launch_bounds__(256) void transpose_kernel(
    const float* __restrict__ support, const float* __restrict__ query,
    unsigned short* __restrict__ qsT) {
  const int bid = blockIdx.x;         // 9216 = 8n * 72pt * 16ct
  const int n    = bid & 7;           // XCD pin
  const int rest = bid >> 3;
  const int pt = rest % 72;
  const int ct = rest / 72;           // 0..15; 32-ch block
  const int p0 = pt * 32;
  const int tid = threadIdx.x;

  __shared__ float tile[32][33];

  const float* plane = ((ct < 8) ? query : support) +
                       ((size_t)n * CC + (ct & 7) * 32) * HW;
#pragma unroll
  for (int j = 0; j < 4; ++j) {
    const int idx = tid + j * 256;
    const int cc = idx >> 5, pp = idx & 31;
    tile[pp][cc] = plane[(size_t)cc * HW + p0 + pp];
  }
  __syncthreads();

  unsigned short* qn = qsT + (size_t)n * NCG * PPL * 8;
  const int cgbase = ((ct < 8) ? 0 : 32) + (ct & 7) * 4;

  if (tid < 128) {
    const int pp  = tid & 31;
    const int cgl = tid >> 5;          // 0..3
    const int s = p0 + pp;
    const int y = s / 48, x = s % 48;
    const int psite = (y + 2) * 52 + (x + 2);
    const float* row = &tile[pp][cgl * 8];
    uint4 w;
    w.x = (unsigned)f2bf(row[0]) | ((unsigned)f2bf(row[1]) << 16);
    w.y = (unsigned)f2bf(row[2]) | ((unsigned)f2bf(row[3]) << 16);
    w.z = (unsigned)f2bf(row[4]) | ((unsigned)f2bf(row[5]) << 16);
    w.w = (unsigned)f2bf(row[6]) | ((unsigned)f2bf(row[7]) << 16);
    *(uint4*)(qn + ((size_t)(cgbase + cgl) * PPL + psite) * 8) = w;
  }

  // zero border: 400 border sites x 4 cg planes, done by pt==0 blocks
  if (pt == 0) {
    const uint4 zz = make_uint4(0u, 0u, 0u, 0u);
    for (int z = tid; z < 1600; z += 256) {
      const int cgl = z / 400;
      const int e   = z % 400;
      int row, col;
      if (e < 104)      { row = e / 52;              col = e % 52; }          // rows 0,1
      else if (e < 208) { row = 50 + (e - 104) / 52; col = (e - 104) % 52; }  // rows 50,51
      else {
        const int f = e - 208;                                               // cols 0,1,50,51
        row = 2 + f / 4;
        const int cs = f % 4;
        col = (cs < 2) ? cs : (48 + cs);
      }
      *(uint4*)(qn + ((size_t)(cgbase + cgl) * PPL + row * 52 + col) * 8) = zz;
    }
  }
}

// ---------------------------------------------------------------------------
// Kernel 2: offset conv, LDS-staged implicit GEMM, 2-phase software pipeline:
// per tap: {issue tap t+1's 8 ds_reads + 4 global A-loads} -> sched_barrier
// -> {tap t's 8 MFMAs}. MFMAs wait on loads issued one tap earlier (counted
// lgkmcnt), so neither LDS nor L2 latency is exposed. Buffer idx = t&1,
// fully unrolled (static). Block = 192 thr (3 waves), 53KB LDS, 3 blocks/CU.
// offs_part[8][N][18][HW] partials. XCD-pinned by n.
// ---------------------------------------------------------------------------
__global__ __launch_bounds__(192, 2) void offset_conv_mfma(
    const unsigned short* __restrict__ qsT,
    const unsigned short* __restrict__ Wm, float* __restrict__ offs_part) {
  const int bid = blockIdx.x;        // 768 = 12rt * 8g * 8n
  const int n  = bid & 7;            // XCD pin
  const int r2 = bid >> 3;           // 0..95
  const int g  = r2 & 7;             // channel group (64 ch)
  const int rt = r2 >> 3;            // 0..11 (4 image rows each)
  const int tid = threadIdx.x;

  __shared__ __align__(16) unsigned short lds[3328 * 8];   // 53,248 B

  // ---- stage: cg 0..7 (abs g*8+cg), padded rows rt*4..rt*4+7, cols 0..51 ----
  const unsigned short* qn = qsT + ((size_t)n * NCG + g * 8) * PPL * 8;
  for (int c = tid; c < 3328; c += 192) {
    const int cg  = c / 416;
    const int rem = c - cg * 416;                    // rr*52 + col
    const uint4 v = *(const uint4*)(qn + ((size_t)cg * PPL + rt * 4 * 52 + rem) * 8);
    *(uint4*)(lds + (size_t)c * 8) = v;
  }
  __syncthreads();

  const int w = tid >> 6;            // wave 0..2
  const int l = tid & 63;
  const int l31 = l & 31;
  const int half = l >> 5;
  const int si0 = w * 64 + l31;      // first site (0..191 within row tile)
  const int si1 = si0 + 32;          // second site
  const int rrA = si0 / 48, xA = si0 % 48;
  const int rrB = si1 / 48, xB = si1 % 48;

  const unsigned short* lbase0 = lds + (half * 416 + rrA * 52 + xA) * 8;
  const unsigned short* lbase1 = lds + (half * 416 + rrB * 52 + xB) * 8;
  const unsigned short* abase = Wm + (size_t)((g * 8 + half) * 32 + l31) * 8;
  // A(t,kk) = abase + t*16384 + kk*512 (shorts)
  // B(t,kk,site) = lbase + kk*6656 + ((t/5)*52 + t%5)*8 (shorts, compile-time)

  f32x16 acc0 = {0.f, 0.f, 0.f, 0.f, 0.f, 0.f, 0.f, 0.f,
                 0.f, 0.f, 0.f, 0.f, 0.f, 0.f, 0.f, 0.f};
  f32x16 acc1 = acc0;

  short8 a[2][4];                    // [t&1][kk]
  short8 b0[2][4], b1[2][4];

  // prologue: tap 0 into buffer 0
#pragma unroll
  for (int kk = 0; kk < 4; ++kk) {
    a[0][kk]  = *(const short8*)(abase + 0 * 16384 + kk * 512);
    b0[0][kk] = *(const short8*)(lbase0 + kk * 6656);
    b1[0][kk] = *(const short8*)(lbase1 + kk * 6656);
  }

#pragma unroll
  for (int t = 0; t < 25; ++t) {
    const int cur = t & 1;
    const int nxt = cur ^ 1;
    if (t < 24) {
      const int tn = t + 1;
      const int loff = ((tn / 5) * 52 + (tn % 5)) * 8;   // compile-time
#pragma unroll
      for (int kk = 0; kk < 4; ++kk) {
        b0[nxt][kk] = *(const short8*)(lbase0 + kk * 6656 + loff);
        b1[nxt][kk] = *(const short8*)(lbase1 + kk * 6656 + loff);
        a[nxt][kk]  = *(const short8*)(abase + tn * 16384 + kk * 512);
      }
    }
    __builtin_amdgcn_sched_barrier(0);
#pragma unroll
    for (int kk = 0; kk < 4; ++kk) {
      acc0 = __builtin_amdgcn_mfma_f32_32x32x16_bf16(a[cur][kk], b0[cur][kk], acc0, 0, 0, 0);
      acc1 = __builtin_amdgcn_mfma_f32_32x32x16_bf16(a[cur][kk], b1[cur][kk], acc1, 0, 0, 0);
    }
  }

  float* dst = offs_part + ((size_t)(g * NN + n) * OCONV) * HW;
  const int s0 = rt * 192 + si0;
  const int s1 = rt * 192 + si1;
#pragma unroll
  for (int r = 0; r < 16; ++r) {
    const int o = (r & 3) + 8 * (r >> 2) + 4 * half;
    if (o < OCONV) {
      dst[(size_t)o * HW + s0] = acc0[r];
      dst[(size_t)o * HW + s1] = acc1[r];
    }
  }
}

// ---------------------------------------------------------------------------
// Kernel 3: fold split-K partials + precompute bilinear params.
// par[n][k][p][8]: {w00,w01,w10,w11 (f32), a00,a01,a10,a11 (int)}. XCD-pinned.
// ---------------------------------------------------------------------------
__global__ __launch_bounds__(256) void param_kernel(
    const float* __restrict__ offs_part, float* __restrict__ par) {
  const int n  = blockIdx.x & 7;       // XCD pin
  const int j  = blockIdx.x >> 3;      // 0..80
  const int il = j * 256 + threadIdx.x;
  const int p = il % HW;
  const int k = il / HW;
  const int y = p / WW, x = p % WW;

  float dy = 0.f, dx = 0.f;
#pragma unroll
  for (int g = 0; g < G1; ++g) {
    const float* base = offs_part + ((size_t)(g * NN + n) * OCONV + 2 * k) * HW + p;
    dy += base[0];
    dx += base[HW];
  }
  const float sy = (float)(y + k / 3 - 1) + dy;
  const float sx = (float)(x + k % 3 - 1) + dx;
  const float y0 = floorf(sy), x0 = floorf(sx);
  const float ly = sy - y0,  lx = sx - x0;
  const float y1 = y0 + 1.f, x1 = x0 + 1.f;
  const float vy0 = (y0 >= 0.f && y0 <= (float)(HH - 1)) ? 1.f : 0.f;
  const float vy1 = (y1 >= 0.f && y1 <= (float)(HH - 1)) ? 1.f : 0.f;
  const float vx0 = (x0 >= 0.f && x0 <= (float)(WW - 1)) ? 1.f : 0.f;
  const float vx1 = (x1 >= 0.f && x1 <= (float)(WW - 1)) ? 1.f : 0.f;
  const int yi0 = min(max((int)y0, 0), HH - 1);
  const int yi1 = min(max((int)y1, 0), HH - 1);
  const int xi0 = min(max((int)x0, 0), WW - 1);
  const int xi1 = min(max((int)x1, 0), WW - 1);

  float* d = par + ((size_t)n * KTAP * HW + il) * 8;
  d[0] = (1.f - ly) * (1.f - lx) * vy0 * vx0;
  d[1] = (1.f - ly) * lx * vy0 * vx1;
  d[2] = ly * (1.f - lx) * vy1 * vx0;
  d[3] = ly * lx * vy1 * vx1;
  int* di = (int*)d;
  di[4] = yi0 * WW + xi0;
  di[5] = yi0 * WW + xi1;
  di[6] = yi1 * WW + xi0;
  di[7] = yi1 * WW + xi1;
}

// ---------------------------------------------------------------------------
// Kernel 4: D[n][m][site] = sum_c wk[o][c][k] * sup[n][c][site], m=k*9+o.
// B = support cg-planes (32..63), padded site addressing. XCD-pinned.
// ---------------------------------------------------------------------------
__global__ __launch_bounds__(256) void deform_gemm(
    const unsigned short* __restrict__ qsT, const unsigned short* __restrict__ wkm,
    float* __restrict__ D) {
  const int bid = blockIdx.x;
  const int n    = bid & 7;           // XCD pin
  const int rest = bid >> 3;          // 0..53
  const int tid = threadIdx.x;
  const int w = tid >> 6;
  const int wid = rest * 4 + w;       // 0..215
  const int st = wid % 72;            // site tile
  const int mt = wid / 72;            // m tile 0..2
  const int l = tid & 63;
  const int lane31 = l & 31;
  const int half = l >> 5;
  const int s = st * 32 + lane31;
  const int psite = (s / 48) * 52 + (s % 48) + 2 * 52 + 2;

  const unsigned short* qn = qsT + (size_t)n * NCG * PPL * 8;
  const unsigned short* asrc = wkm + (size_t)(half * 32 + lane31) * 8;

  f32x16 acc = {0.f, 0.f, 0.f, 0.f, 0.f, 0.f, 0.f, 0.f,
                0.f, 0.f, 0.f, 0.f, 0.f, 0.f, 0.f, 0.f};

#pragma unroll
  for (int cb = 0; cb < 16; ++cb) {
    const int cg = 32 + cb * 2 + half;
    const short8 b = *(const short8*)(qn + ((size_t)cg * PPL + psite) * 8);
    const short8 a = *(const short8*)(asrc + (size_t)((mt * 16 + cb) * 2) * 256);
    acc = __builtin_amdgcn_mfma_f32_32x32x16_bf16(a, b, acc, 0, 0, 0);
  }

  float* Dn = D + (size_t)n * MM * HW;
#pragma unroll
  for (int r = 0; r < 16; ++r) {
    const int m = mt * 32 + (r & 3) + 8 * (r >> 2) + 4 * half;
    Dn[(size_t)m * HW + s] = acc[r];
  }
}

// ---------------------------------------------------------------------------
// Kernel 5: combine + sigmoid. One thread per output element. XCD-pinned.
// ---------------------------------------------------------------------------
__global__ __launch_bounds__(256) void deform_combine(
    const float* __restrict__ D, const float* __restrict__ par,
    float* __restrict__ out) {
  const int bid = blockIdx.x;          // 648 = 81 * 8n
  const int n  = bid & 7;              // XCD pin
  const int rr = bid >> 3;             // 0..80
  const int o  = rr / 9;
  const int p  = (rr % 9) * 256 + threadIdx.x;

  const float* Dn = D + (size_t)n * MM * HW;
  const float* pb = par + ((size_t)n * KTAP * HW + p) * 8;

  float s = 0.f;
#pragma unroll
  for (int k = 0; k < KTAP; ++k) {
    const float4 wv = *(const float4*)(pb + (size_t)k * HW * 8);
    const int4  av = *(const int4*)(pb + (size_t)k * HW * 8 + 4);
    const float* base = Dn + (size_t)(k * 9 + o) * HW;
    s += wv.x * base[av.x] + wv.y * base[av.y] +
         wv.z * base[av.z] + wv.w * base[av.w];
  }
  out[((size_t)n * KTAP + o) * HW + p] = 1.f / (1.f + __expf(-s));
}

extern "C" void kernel_launch(void* const* d_in, const int* in_sizes, int n_in,
                              void* d_out, int out_size, void* d_ws, size_t ws_size,
                              hipStream_t stream) {
  const float* support  = (const float*)d_in[0];
  const float* query    = (const float*)d_in[1];
  const float* w_off    = (const float*)d_in[2];
  const float* w_kernel = (const float*)d_in[3];
  float* out = (float*)d_out;

  // ws layout (float units), ~39 MB:
  // [qsT 22.2MB][par 5.3MB][Wm 0.82MB][wkm 0.1MB][X: offs_part 10.6MB / D 7.1MB]
  float* base = (float*)d_ws;
  unsigned short* qsT = (unsigned short*)base;                  // 8*64*PPL*8 bf16
  float* par = base + (size_t)NN * NCG * PPL * 8 / 2;           // NN*9*HW*8 f
  float* tail = par + (size_t)NN * KTAP * HW * 8;
  unsigned short* Wm  = (unsigned short*)tail;                  // 409600 bf16 = 204800 f
  unsigned short* wkm = (unsigned short*)(tail + 204800);       // 49152 bf16 = 24576 f
  float* X = tail + 204800 + 24576;
  float* offs_part = X;                                         // G1*NSZ f (early)
  float* D = X;                                                 // NN*MM*HW f (late, aliases)

  prep_weights<<<1696, 256, 0, stream>>>(w_off, w_kernel, Wm, wkm);
  transpose_kernel<<<8 * 72 * 16, 256, 0, stream>>>(support, query, qsT);
  offset_conv_mfma<<<768, 192, 0, stream>>>(qsT, Wm, offs_part);
  param_kernel<<<81 * 8, 256, 0, stream>>>(offs_part, par);
  deform_gemm<<<54 * 8, 256, 0, stream>>>(qsT, wkm, D);   // D aliases offs_part (dead)
  deform_combine<<<81 * 8, 256, 0, stream>>>(D, par, out);
}

// Round 17
// 57.680 us; speedup vs baseline: 1.4794x; 1.0685x over previous
//
#include <hip/hip_runtime.h>
#include <math.h>

#define NN 8
#define CC 256        // channels per tensor (concat input has 2*CC = 512)
#define HH 48
#define WW 48
#define HW 2304       // 48*48
#define OCONV 18      // offset-conv output channels (2*K)
#define KTAP 9        // deform taps
#define G1 8          // split-K groups for offset conv (512/8 = 64 ch/group)
#define NSZ (NN * OCONV * HW)   // 331776
#define MM 96         // padded deform-GEMM rows (81 used)
#define NCG 64        // 512 ch / 8
#define PPL 2704      // padded plane sites: 52*52 (2-site zero border)

typedef __attribute__((ext_vector_type(8))) short short8;   // 8 bf16 (4 VGPRs)
typedef __attribute__((ext_vector_type(16))) float f32x16;  // 32x32 MFMA acc

static __device__ __forceinline__ unsigned short f2bf(float f) {
  unsigned u = __float_as_uint(f);
  unsigned r = (u + 0x7fffu + ((u >> 16) & 1u)) >> 16;   // round-to-nearest-even
  return (unsigned short)r;
}

// ---------------------------------------------------------------------------
// Kernel 1 (merged): blocks 0..9215 transpose query+support ->
// qsT[n][cg][52x52 padded][8ch] bf16 (2-site zero border, XCD-pinned);
// blocks 9216..10911 do weight prep (Wm conv A-frags, wkm deform A-frags).
// ---------------------------------------------------------------------------
__global__ __launch_bounds__(256) void transpose_prep_kernel(
    const float* __restrict__ support, const float* __restrict__ query,
    const float* __restrict__ w_off, const float* __restrict__ w_kernel,
    unsigned short* __restrict__ qsT, unsigned short* __restrict__ Wm,
    unsigned short* __restrict__ wkm) {
  const int bid = blockIdx.x;
  const int tid = threadIdx.x;

  if (bid >= 9216) {                  // ---- weight prep part ----
    const int b = bid - 9216;
    if (b < 1600) {
      const int i = b * 256 + tid;    // < 409600
      const int j  = i & 7;
      const int o  = (i >> 3) & 31;
      const int cb = (i >> 8) & 63;
      const int t  = i >> 14;
      float v = 0.f;
      if (o < OCONV) v = w_off[(size_t)(o * (2 * CC) + cb * 8 + j) * 25 + t];
      Wm[i] = f2bf(v);
    } else {
      const int i = (b - 1600) * 256 + tid;
      if (i < 3 * 16 * 2 * 32 * 8) {
        const int j    = i & 7;
        const int r    = (i >> 3) & 31;
        const int half = (i >> 8) & 1;
        const int cb   = (i >> 9) & 15;
        const int mt   = i >> 13;
        const int m = mt * 32 + r;
        const int c = cb * 16 + half * 8 + j;
        float v = 0.f;
        if (m < 81) {
          const int k = m / 9, o = m % 9;
          v = w_kernel[(size_t)(o * CC + c) * KTAP + k];
        }
        wkm[i] = f2bf(v);
      }
    }
    return;
  }

  // ---- transpose part (bid 0..9215 = 8n * 72pt * 16ct) ----
  const int n    = bid & 7;           // XCD pin
  const int rest = bid >> 3;
  const int pt = rest % 72;
  const int ct = rest / 72;           // 0..15; 32-ch block
  const int p0 = pt * 32;

  __shared__ float tile[32][33];

  const float* plane = ((ct < 8) ? query : support) +
                       ((size_t)n * CC + (ct & 7) * 32) * HW;
#pragma unroll
  for (int j = 0; j < 4; ++j) {
    const int idx = tid + j * 256;
    const int cc = idx >> 5, pp = idx & 31;
    tile[pp][cc] = plane[(size_t)cc * HW + p0 + pp];
  }
  __syncthreads();

  unsigned short* qn = qsT + (size_t)n * NCG * PPL * 8;
  const int cgbase = ((ct < 8) ? 0 : 32) + (ct & 7) * 4;

  if (tid < 128) {
    const int pp  = tid & 31;
    const int cgl = tid >> 5;          // 0..3
    const int s = p0 + pp;
    const int y = s / 48, x = s % 48;
    const int psite = (y + 2) * 52 + (x + 2);
    const float* row = &tile[pp][cgl * 8];
    uint4 w;
    w.x = (unsigned)f2bf(row[0]) | ((unsigned)f2bf(row[1]) << 16);
    w.y = (unsigned)f2bf(row[2]) | ((unsigned)f2bf(row[3]) << 16);
    w.z = (unsigned)f2bf(row[4]) | ((unsigned)f2bf(row[5]) << 16);
    w.w = (unsigned)f2bf(row[6]) | ((unsigned)f2bf(row[7]) << 16);
    *(uint4*)(qn + ((size_t)(cgbase + cgl) * PPL + psite) * 8) = w;
  }

  // zero border: 400 border sites x 4 cg planes, done by pt==0 blocks
  if (pt == 0) {
    const uint4 zz = make_uint4(0u, 0u, 0u, 0u);
    for (int z = tid; z < 1600; z += 256) {
      const int cgl = z / 400;
      const int e   = z % 400;
      int row, col;
      if (e < 104)      { row = e / 52;              col = e % 52; }          // rows 0,1
      else if (e < 208) { row = 50 + (e - 104) / 52; col = (e - 104) % 52; }  // rows 50,51
      else {
        const int f = e - 208;                                               // cols 0,1,50,51
        row = 2 + f / 4;
        const int cs = f % 4;
        col = (cs < 2) ? cs : (48 + cs);
      }
      *(uint4*)(qn + ((size_t)(cgbase + cgl) * PPL + row * 52 + col) * 8) = zz;
    }
  }
}

// ---------------------------------------------------------------------------
// Kernel 2: offset conv, LDS-staged implicit GEMM, asymmetric-depth pipeline:
// B (LDS, ~120cyc) double-buffered 1 tap ahead; A (global/L2, ~200cyc)
// triple-buffered 2 taps ahead. sched_barrier(0) between the load phase and
// the MFMA phase of each tap pins the schedule. Block = 192 thr (3 waves),
// 53KB LDS, 3 blocks/CU. offs_part[8][N][18][HW] partials. XCD-pinned by n.
// ---------------------------------------------------------------------------
__global__ __launch_bounds__(192, 2) void offset_conv_mfma(
    const unsigned short* __restrict__ qsT,
    const unsigned short* __restrict__ Wm, float* __restrict__ offs_part) {
  const int bid = blockIdx.x;        // 768 = 12rt * 8g * 8n
  const int n  = bid & 7;            // XCD pin
  const int r2 = bid >> 3;           // 0..95
  const int g  = r2 & 7;             // channel group (64 ch)
  const int rt = r2 >> 3;            // 0..11 (4 image rows each)
  const int tid = threadIdx.x;

  __shared__ __align__(16) unsigned short lds[3328 * 8];   // 53,248 B

  // ---- stage: cg 0..7 (abs g*8+cg), padded rows rt*4..rt*4+7, cols 0..51 ----
  const unsigned short* qn = qsT + ((size_t)n * NCG + g * 8) * PPL * 8;
  for (int c = tid; c < 3328; c += 192) {
    const int cg  = c / 416;
    const int rem = c - cg * 416;                    // rr*52 + col
    const uint4 v = *(const uint4*)(qn + ((size_t)cg * PPL + rt * 4 * 52 + rem) * 8);
    *(uint4*)(lds + (size_t)c * 8) = v;
  }
  __syncthreads();

  const int w = tid >> 6;            // wave 0..2
  const int l = tid & 63;
  const int l31 = l & 31;
  const int half = l >> 5;
  const int si0 = w * 64 + l31;      // first site (0..191 within row tile)
  const int si1 = si0 + 32;          // second site
  const int rrA = si0 / 48, xA = si0 % 48;
  const int rrB = si1 / 48, xB = si1 % 48;

  const unsigned short* lbase0 = lds + (half * 416 + rrA * 52 + xA) * 8;
  const unsigned short* lbase1 = lds + (half * 416 + rrB * 52 + xB) * 8;
  const unsigned short* abase = Wm + (size_t)((g * 8 + half) * 32 + l31) * 8;
  // A(t,kk) = abase + t*16384 + kk*512 (shorts)
  // B(t,kk,site) = lbase + kk*6656 + ((t/5)*52 + t%5)*8 (shorts, compile-time)

  f32x16 acc0 = {0.f, 0.f, 0.f, 0.f, 0.f, 0.f, 0.f, 0.f,
                 0.f, 0.f, 0.f, 0.f, 0.f, 0.f, 0.f, 0.f};
  f32x16 acc1 = acc0;

  short8 a[3][4];                    // [t%3][kk] — A prefetched 2 taps ahead
  short8 b0[2][4], b1[2][4];         // [t&1][kk] — B prefetched 1 tap ahead

  // prologue: A taps 0,1; B tap 0
#pragma unroll
  for (int kk = 0; kk < 4; ++kk) {
    a[0][kk]  = *(const short8*)(abase + 0 * 16384 + kk * 512);
    a[1][kk]  = *(const short8*)(abase + 1 * 16384 + kk * 512);
    b0[0][kk] = *(const short8*)(lbase0 + kk * 6656);
    b1[0][kk] = *(const short8*)(lbase1 + kk * 6656);
  }

#pragma unroll
  for (int t = 0; t < 25; ++t) {
    const int bc = t & 1;            // current B buffer
    const int ac = t % 3;            // current A buffer
    if (t < 24) {
      const int tn = t + 1;
      const int loff = ((tn / 5) * 52 + (tn % 5)) * 8;   // compile-time
#pragma unroll
      for (int kk = 0; kk < 4; ++kk) {
        b0[bc ^ 1][kk] = *(const short8*)(lbase0 + kk * 6656 + loff);
        b1[bc ^ 1][kk] = *(const short8*)(lbase1 + kk * 6656 + loff);
      }
    }
    if (t < 23) {
      const int ta = t + 2;
#pragma unroll
      for (int kk = 0; kk < 4; ++kk)
        a[(t + 2) % 3][kk] = *(const short8*)(abase + ta * 16384 + kk * 512);
    }
    __builtin_amdgcn_sched_barrier(0);
#pragma unroll
    for (int kk = 0; kk < 4; ++kk) {
      acc0 = __builtin_amdgcn_mfma_f32_32x32x16_bf16(a[ac][kk], b0[bc][kk], acc0, 0, 0, 0);
      acc1 = __builtin_amdgcn_mfma_f32_32x32x16_bf16(a[ac][kk], b1[bc][kk], acc1, 0, 0, 0);
    }
  }

  float* dst = offs_part + ((size_t)(g * NN + n) * OCONV) * HW;
  const int s0 = rt * 192 + si0;
  const int s1 = rt * 192 + si1;
#pragma unroll
  for (int r = 0; r < 16; ++r) {
    const int o = (r & 3) + 8 * (r >> 2) + 4 * half;
    if (o < OCONV) {
      dst[(size_t)o * HW + s0] = acc0[r];
      dst[(size_t)o * HW + s1] = acc1[r];
    }
  }
}

// ---------------------------------------------------------------------------
// Kernel 3: fold split-K partials + precompute bilinear params.
// par[n][k][p][8]: {w00,w01,w10,w11 (f32), a00,a01,a10,a11 (int)}. XCD-pinned.
// ---------------------------------------------------------------------------
__global__ __launch_bounds__(256) void param_kernel(
    const float* __restrict__ offs_part, float* __restrict__ par) {
  const int n  = blockIdx.x & 7;       // XCD pin
  const int j  = blockIdx.x >> 3;      // 0..80
  const int il = j * 256 + threadIdx.x;
  const int p = il % HW;
  const int k = il / HW;
  const int y = p / WW, x = p % WW;

  float dy = 0.f, dx = 0.f;
#pragma unroll
  for (int g = 0; g < G1; ++g) {
    const float* base = offs_part + ((size_t)(g * NN + n) * OCONV + 2 * k) * HW + p;
    dy += base[0];
    dx += base[HW];
  }
  const float sy = (float)(y + k / 3 - 1) + dy;
  const float sx = (float)(x + k % 3 - 1) + dx;
  const float y0 = floorf(sy), x0 = floorf(sx);
  const float ly = sy - y0,  lx = sx - x0;
  const float y1 = y0 + 1.f, x1 = x0 + 1.f;
  const float vy0 = (y0 >= 0.f && y0 <= (float)(HH - 1)) ? 1.f : 0.f;
  const float vy1 = (y1 >= 0.f && y1 <= (float)(HH - 1)) ? 1.f : 0.f;
  const float vx0 = (x0 >= 0.f && x0 <= (float)(WW - 1)) ? 1.f : 0.f;
  const float vx1 = (x1 >= 0.f && x1 <= (float)(WW - 1)) ? 1.f : 0.f;
  const int yi0 = min(max((int)y0, 0), HH - 1);
  const int yi1 = min(max((int)y1, 0), HH - 1);
  const int xi0 = min(max((int)x0, 0), WW - 1);
  const int xi1 = min(max((int)x1, 0), WW - 1);

  float* d = par + ((size_t)n * KTAP * HW + il) * 8;
  d[0] = (1.f - ly) * (1.f - lx) * vy0 * vx0;
  d[1] = (1.f - ly) * lx * vy0 * vx1;
  d[2] = ly * (1.f - lx) * vy1 * vx0;
  d[3] = ly * lx * vy1 * vx1;
  int* di = (int*)d;
  di[4] = yi0 * WW + xi0;
  di[5] = yi0 * WW + xi1;
  di[6] = yi1 * WW + xi0;
  di[7] = yi1 * WW + xi1;
}

// ---------------------------------------------------------------------------
// Kernel 4: D[n][m][site] = sum_c wk[o][c][k] * sup[n][c][site], m=k*9+o.
// B = support cg-planes (32..63), padded site addressing. XCD-pinned.
// ---------------------------------------------------------------------------
__global__ __launch_bounds__(256) void deform_gemm(
    const unsigned short* __restrict__ qsT, const unsigned short* __restrict__ wkm,
    float* __restrict__ D) {
  const int bid = blockIdx.x;
  const int n    = bid & 7;           // XCD pin
  const int rest = bid >> 3;          // 0..53
  const int tid = threadIdx.x;
  const int w = tid >> 6;
  const int wid = rest * 4 + w;       // 0..215
  const int st = wid % 72;            // site tile
  const int mt = wid / 72;            // m tile 0..2
  const int l = tid & 63;
  const int lane31 = l & 31;
  const int half = l >> 5;
  const int s = st * 32 + lane31;
  const int psite = (s / 48) * 52 + (s % 48) + 2 * 52 + 2;

  const unsigned short* qn = qsT + (size_t)n * NCG * PPL * 8;
  const unsigned short* asrc = wkm + (size_t)(half * 32 + lane31) * 8;

  f32x16 acc = {0.f, 0.f, 0.f, 0.f, 0.f, 0.f, 0.f, 0.f,
                0.f, 0.f, 0.f, 0.f, 0.f, 0.f, 0.f, 0.f};

#pragma unroll
  for (int cb = 0; cb < 16; ++cb) {
    const int cg = 32 + cb * 2 + half;
    const short8 b = *(const short8*)(qn + ((size_t)cg * PPL + psite) * 8);
    const short8 a = *(const short8*)(asrc + (size_t)((mt * 16 + cb) * 2) * 256);
    acc = __builtin_amdgcn_mfma_f32_32x32x16_bf16(a, b, acc, 0, 0, 0);
  }

  float* Dn = D + (size_t)n * MM * HW;
#pragma unroll
  for (int r = 0; r < 16; ++r) {
    const int m = mt * 32 + (r & 3) + 8 * (r >> 2) + 4 * half;
    Dn[(size_t)m * HW + s] = acc[r];
  }
}

// ---------------------------------------------------------------------------
// Kernel 5: combine + sigmoid. One thread per output element. XCD-pinned.
// ---------------------------------------------------------------------------
__global__ __launch_bounds__(256) void deform_combine(
    const float* __restrict__ D, const float* __restrict__ par,
    float* __restrict__ out) {
  const int bid = blockIdx.x;          // 648 = 81 * 8n
  const int n  = bid & 7;              // XCD pin
  const int rr = bid >> 3;             // 0..80
  const int o  = rr / 9;
  const int p  = (rr % 9) * 256 + threadIdx.x;

  const float* Dn = D + (size_t)n * MM * HW;
  const float* pb = par + ((size_t)n * KTAP * HW + p) * 8;

  float s = 0.f;
#pragma unroll
  for (int k = 0; k < KTAP; ++k) {
    const float4 wv = *(const float4*)(pb + (size_t)k * HW * 8);
    const int4  av = *(const int4*)(pb + (size_t)k * HW * 8 + 4);
    const float* base = Dn + (size_t)(k * 9 + o) * HW;
    s += wv.x * base[av.x] + wv.y * base[av.y] +
         wv.z * base[av.z] + wv.w * base[av.w];
  }
  out[((size_t)n * KTAP + o) * HW + p] = 1.f / (1.f + __expf(-s));
}

extern "C" void kernel_launch(void* const* d_in, const int* in_sizes, int n_in,
                              void* d_out, int out_size, void* d_ws, size_t ws_size,
                              hipStream_t stream) {
  const float* support  = (const float*)d_in[0];
  const float* query    = (const float*)d_in[1];
  const float* w_off    = (const float*)d_in[2];
  const float* w_kernel = (const float*)d_in[3];
  float* out = (float*)d_out;

  // ws layout (float units), ~39 MB:
  // [qsT 22.2MB][par 5.3MB][Wm 0.82MB][wkm 0.1MB][X: offs_part 10.6MB / D 7.1MB]
  float* base = (float*)d_ws;
  unsigned short* qsT = (unsigned short*)base;                  // 8*64*PPL*8 bf16
  float* par = base + (size_t)NN * NCG * PPL * 8 / 2;           // NN*9*HW*8 f
  float* tail = par + (size_t)NN * KTAP * HW * 8;
  unsigned short* Wm  = (unsigned short*)tail;                  // 409600 bf16 = 204800 f
  unsigned short* wkm = (unsigned short*)(tail + 204800);       // 49152 bf16 = 24576 f
  float* X = tail + 204800 + 24576;
  float* offs_part = X;                                         // G1*NSZ f (early)
  float* D = X;                                                 // NN*MM*HW f (late, aliases)

  transpose_prep_kernel<<<9216 + 1696, 256, 0, stream>>>(
      support, query, w_off, w_kernel, qsT, Wm, wkm);
  offset_conv_mfma<<<768, 192, 0, stream>>>(qsT, Wm, offs_part);
  param_kernel<<<81 * 8, 256, 0, stream>>>(offs_part, par);
  deform_gemm<<<54 * 8, 256, 0, stream>>>(qsT, wkm, D);   // D aliases offs_part (dead)
  deform_combine<<<81 * 8, 256, 0, stream>>>(D, par, out);
}

// Round 18
// 56.842 us; speedup vs baseline: 1.5012x; 1.0147x over previous
//
#include <hip/hip_runtime.h>
#include <math.h>

#define NN 8
#define CC 256        // channels per tensor (concat input has 2*CC = 512)
#define HH 48
#define WW 48
#define HW 2304       // 48*48
#define OCONV 18      // offset-conv output channels (2*K)
#define KTAP 9        // deform taps
#define G1 16         // split-K groups for offset conv (512/16 = 32 ch/group)
#define NSZ (NN * OCONV * HW)   // 331776
#define MM 96         // padded deform-GEMM rows (81 used)
#define NCG 64        // 512 ch / 8
#define PPL 2704      // padded plane sites: 52*52 (2-site zero border)

typedef __attribute__((ext_vector_type(8))) short short8;   // 8 bf16 (4 VGPRs)
typedef __attribute__((ext_vector_type(16))) float f32x16;  // 32x32 MFMA acc

static __device__ __forceinline__ unsigned short f2bf(float f) {
  unsigned u = __float_as_uint(f);
  unsigned r = (u + 0x7fffu + ((u >> 16) & 1u)) >> 16;   // round-to-nearest-even
  return (unsigned short)r;
}

// ---------------------------------------------------------------------------
// Kernel 1 (merged): blocks 0..9215 transpose query+support ->
// qsT[n][cg][52x52 padded][8ch] bf16 (2-site zero border, XCD-pinned);
// blocks 9216..10911 do weight prep (Wm conv A-frags, wkm deform A-frags).
// ---------------------------------------------------------------------------
__global__ __launch_bounds__(256) void transpose_prep_kernel(
    const float* __restrict__ support, const float* __restrict__ query,
    const float* __restrict__ w_off, const float* __restrict__ w_kernel,
    unsigned short* __restrict__ qsT, unsigned short* __restrict__ Wm,
    unsigned short* __restrict__ wkm) {
  const int bid = blockIdx.x;
  const int tid = threadIdx.x;

  if (bid >= 9216) {                  // ---- weight prep part ----
    const int b = bid - 9216;
    if (b < 1600) {
      const int i = b * 256 + tid;    // < 409600
      const int j  = i & 7;
      const int o  = (i >> 3) & 31;
      const int cb = (i >> 8) & 63;
      const int t  = i >> 14;
      float v = 0.f;
      if (o < OCONV) v = w_off[(size_t)(o * (2 * CC) + cb * 8 + j) * 25 + t];
      Wm[i] = f2bf(v);
    } else {
      const int i = (b - 1600) * 256 + tid;
      if (i < 3 * 16 * 2 * 32 * 8) {
        const int j    = i & 7;
        const int r    = (i >> 3) & 31;
        const int half = (i >> 8) & 1;
        const int cb   = (i >> 9) & 15;
        const int mt   = i >> 13;
        const int m = mt * 32 + r;
        const int c = cb * 16 + half * 8 + j;
        float v = 0.f;
        if (m < 81) {
          const int k = m / 9, o = m % 9;
          v = w_kernel[(size_t)(o * CC + c) * KTAP + k];
        }
        wkm[i] = f2bf(v);
      }
    }
    return;
  }

  // ---- transpose part (bid 0..9215 = 8n * 72pt * 16ct) ----
  const int n    = bid & 7;           // XCD pin
  const int rest = bid >> 3;
  const int pt = rest % 72;
  const int ct = rest / 72;           // 0..15; 32-ch block
  const int p0 = pt * 32;

  __shared__ float tile[32][33];

  const float* plane = ((ct < 8) ? query : support) +
                       ((size_t)n * CC + (ct & 7) * 32) * HW;
#pragma unroll
  for (int j = 0; j < 4; ++j) {
    const int idx = tid + j * 256;
    const int cc = idx >> 5, pp = idx & 31;
    tile[pp][cc] = plane[(size_t)cc * HW + p0 + pp];
  }
  __syncthreads();

  unsigned short* qn = qsT + (size_t)n * NCG * PPL * 8;
  const int cgbase = ((ct < 8) ? 0 : 32) + (ct & 7) * 4;

  if (tid < 128) {
    const int pp  = tid & 31;
    const int cgl = tid >> 5;          // 0..3
    const int s = p0 + pp;
    const int y = s / 48, x = s % 48;
    const int psite = (y + 2) * 52 + (x + 2);
    const float* row = &tile[pp][cgl * 8];
    uint4 w;
    w.x = (unsigned)f2bf(row[0]) | ((unsigned)f2bf(row[1]) << 16);
    w.y = (unsigned)f2bf(row[2]) | ((unsigned)f2bf(row[3]) << 16);
    w.z = (unsigned)f2bf(row[4]) | ((unsigned)f2bf(row[5]) << 16);
    w.w = (unsigned)f2bf(row[6]) | ((unsigned)f2bf(row[7]) << 16);
    *(uint4*)(qn + ((size_t)(cgbase + cgl) * PPL + psite) * 8) = w;
  }

  // zero border: 400 border sites x 4 cg planes, done by pt==0 blocks
  if (pt == 0) {
    const uint4 zz = make_uint4(0u, 0u, 0u, 0u);
    for (int z = tid; z < 1600; z += 256) {
      const int cgl = z / 400;
      const int e   = z % 400;
      int row, col;
      if (e < 104)      { row = e / 52;              col = e % 52; }          // rows 0,1
      else if (e < 208) { row = 50 + (e - 104) / 52; col = (e - 104) % 52; }  // rows 50,51
      else {
        const int f = e - 208;                                               // cols 0,1,50,51
        row = 2 + f / 4;
        const int cs = f % 4;
        col = (cs < 2) ? cs : (48 + cs);
      }
      *(uint4*)(qn + ((size_t)(cgbase + cgl) * PPL + row * 52 + col) * 8) = zz;
    }
  }
}

// ---------------------------------------------------------------------------
// Kernel 2: offset conv, LDS-staged implicit GEMM, asymmetric-depth pipeline,
// G1=16 (32 ch/group) for 2x occupancy: 4 cg staged = 26.6KB LDS, grid 1536
// = 6 blocks/CU (LDS exact fit 159.7/160KB), 4.5 waves/SIMD. Per tap:
// {4 ds_reads + 2 A-loads prefetched (B 1 tap, A 2 taps ahead)} ->
// sched_barrier -> {4 MFMAs}. offs_part[16][N][18][HW]. XCD-pinned by n.
// ---------------------------------------------------------------------------
__global__ __launch_bounds__(192, 2) void offset_conv_mfma(
    const unsigned short* __restrict__ qsT,
    const unsigned short* __restrict__ Wm, float* __restrict__ offs_part) {
  const int bid = blockIdx.x;        // 1536 = 12rt * 16g * 8n
  const int n  = bid & 7;            // XCD pin
  const int r2 = bid >> 3;           // 0..191
  const int g  = r2 & 15;            // channel group (32 ch)
  const int rt = r2 >> 4;            // 0..11 (4 image rows each)
  const int tid = threadIdx.x;

  __shared__ __align__(16) unsigned short lds[1664 * 8];   // 26,624 B

  // ---- stage: cg 0..3 (abs g*4+cg), padded rows rt*4..rt*4+7, cols 0..51 ----
  const unsigned short* qn = qsT + ((size_t)n * NCG + g * 4) * PPL * 8;
  for (int c = tid; c < 1664; c += 192) {
    const int cg  = c / 416;
    const int rem = c - cg * 416;                    // rr*52 + col
    const uint4 v = *(const uint4*)(qn + ((size_t)cg * PPL + rt * 4 * 52 + rem) * 8);
    *(uint4*)(lds + (size_t)c * 8) = v;
  }
  __syncthreads();

  const int w = tid >> 6;            // wave 0..2
  const int l = tid & 63;
  const int l31 = l & 31;
  const int half = l >> 5;
  const int si0 = w * 64 + l31;      // first site (0..191 within row tile)
  const int si1 = si0 + 32;          // second site
  const int rrA = si0 / 48, xA = si0 % 48;
  const int rrB = si1 / 48, xB = si1 % 48;

  const unsigned short* lbase0 = lds + (half * 416 + rrA * 52 + xA) * 8;
  const unsigned short* lbase1 = lds + (half * 416 + rrB * 52 + xB) * 8;
  const unsigned short* abase = Wm + (size_t)((g * 4 + half) * 32 + l31) * 8;
  // A(t,kk) = abase + t*16384 + kk*512 (shorts); cb = g*4 + kk*2 + half
  // B(t,kk,site) = lbase + kk*6656 + ((t/5)*52 + t%5)*8 (shorts, compile-time)

  f32x16 acc0 = {0.f, 0.f, 0.f, 0.f, 0.f, 0.f, 0.f, 0.f,
                 0.f, 0.f, 0.f, 0.f, 0.f, 0.f, 0.f, 0.f};
  f32x16 acc1 = acc0;

  short8 a[3][2];                    // [t%3][kk] — A prefetched 2 taps ahead
  short8 b0[2][2], b1[2][2];         // [t&1][kk] — B prefetched 1 tap ahead

  // prologue: A taps 0,1; B tap 0
#pragma unroll
  for (int kk = 0; kk < 2; ++kk) {
    a[0][kk]  = *(const short8*)(abase + 0 * 16384 + kk * 512);
    a[1][kk]  = *(const short8*)(abase + 1 * 16384 + kk * 512);
    b0[0][kk] = *(const short8*)(lbase0 + kk * 6656);
    b1[0][kk] = *(const short8*)(lbase1 + kk * 6656);
  }

#pragma unroll
  for (int t = 0; t < 25; ++t) {
    const int bc = t & 1;            // current B buffer
    const int ac = t % 3;            // current A buffer
    if (t < 24) {
      const int tn = t + 1;
      const int loff = ((tn / 5) * 52 + (tn % 5)) * 8;   // compile-time
#pragma unroll
      for (int kk = 0; kk < 2; ++kk) {
        b0[bc ^ 1][kk] = *(const short8*)(lbase0 + kk * 6656 + loff);
        b1[bc ^ 1][kk] = *(const short8*)(lbase1 + kk * 6656 + loff);
      }
    }
    if (t < 23) {
      const int ta = t + 2;
#pragma unroll
      for (int kk = 0; kk < 2; ++kk)
        a[(t + 2) % 3][kk] = *(const short8*)(abase + ta * 16384 + kk * 512);
    }
    __builtin_amdgcn_sched_barrier(0);
#pragma unroll
    for (int kk = 0; kk < 2; ++kk) {
      acc0 = __builtin_amdgcn_mfma_f32_32x32x16_bf16(a[ac][kk], b0[bc][kk], acc0, 0, 0, 0);
      acc1 = __builtin_amdgcn_mfma_f32_32x32x16_bf16(a[ac][kk], b1[bc][kk], acc1, 0, 0, 0);
    }
  }

  float* dst = offs_part + ((size_t)(g * NN + n) * OCONV) * HW;
  const int s0 = rt * 192 + si0;
  const int s1 = rt * 192 + si1;
#pragma unroll
  for (int r = 0; r < 16; ++r) {
    const int o = (r & 3) + 8 * (r >> 2) + 4 * half;
    if (o < OCONV) {
      dst[(size_t)o * HW + s0] = acc0[r];
      dst[(size_t)o * HW + s1] = acc1[r];
    }
  }
}

// ---------------------------------------------------------------------------
// Kernel 3: fold split-K partials + precompute bilinear params.
// par[n][k][p][8]: {w00,w01,w10,w11 (f32), a00,a01,a10,a11 (int)}. XCD-pinned.
// ---------------------------------------------------------------------------
__global__ __launch_bounds__(256) void param_kernel(
    const float* __restrict__ offs_part, float* __restrict__ par) {
  const int n  = blockIdx.x & 7;       // XCD pin
  const int j  = blockIdx.x >> 3;      // 0..80
  const int il = j * 256 + threadIdx.x;
  const int p = il % HW;
  const int k = il / HW;
  const int y = p / WW, x = p % WW;

  float dy = 0.f, dx = 0.f;
#pragma unroll
  for (int g = 0; g < G1; ++g) {
    const float* base = offs_part + ((size_t)(g * NN + n) * OCONV + 2 * k) * HW + p;
    dy += base[0];
    dx += base[HW];
  }
  const float sy = (float)(y + k / 3 - 1) + dy;
  const float sx = (float)(x + k % 3 - 1) + dx;
  const float y0 = floorf(sy), x0 = floorf(sx);
  const float ly = sy - y0,  lx = sx - x0;
  const float y1 = y0 + 1.f, x1 = x0 + 1.f;
  const float vy0 = (y0 >= 0.f && y0 <= (float)(HH - 1)) ? 1.f : 0.f;
  const float vy1 = (y1 >= 0.f && y1 <= (float)(HH - 1)) ? 1.f : 0.f;
  const float vx0 = (x0 >= 0.f && x0 <= (float)(WW - 1)) ? 1.f : 0.f;
  const float vx1 = (x1 >= 0.f && x1 <= (float)(WW - 1)) ? 1.f : 0.f;
  const int yi0 = min(max((int)y0, 0), HH - 1);
  const int yi1 = min(max((int)y1, 0), HH - 1);
  const int xi0 = min(max((int)x0, 0), WW - 1);
  const int xi1 = min(max((int)x1, 0), WW - 1);

  float* d = par + ((size_t)n * KTAP * HW + il) * 8;
  d[0] = (1.f - ly) * (1.f - lx) * vy0 * vx0;
  d[1] = (1.f - ly) * lx * vy0 * vx1;
  d[2] = ly * (1.f - lx) * vy1 * vx0;
  d[3] = ly * lx * vy1 * vx1;
  int* di = (int*)d;
  di[4] = yi0 * WW + xi0;
  di[5] = yi0 * WW + xi1;
  di[6] = yi1 * WW + xi0;
  di[7] = yi1 * WW + xi1;
}

// ---------------------------------------------------------------------------
// Kernel 4: D[n][m][site] = sum_c wk[o][c][k] * sup[n][c][site], m=k*9+o.
// B = support cg-planes (32..63), padded site addressing. XCD-pinned.
// ---------------------------------------------------------------------------
__global__ __launch_bounds__(256) void deform_gemm(
    const unsigned short* __restrict__ qsT, const unsigned short* __restrict__ wkm,
    float* __restrict__ D) {
  const int bid = blockIdx.x;
  const int n    = bid & 7;           // XCD pin
  const int rest = bid >> 3;          // 0..53
  const int tid = threadIdx.x;
  const int w = tid >> 6;
  const int wid = rest * 4 + w;       // 0..215
  const int st = wid % 72;            // site tile
  const int mt = wid / 72;            // m tile 0..2
  const int l = tid & 63;
  const int lane31 = l & 31;
  const int half = l >> 5;
  const int s = st * 32 + lane31;
  const int psite = (s / 48) * 52 + (s % 48) + 2 * 52 + 2;

  const unsigned short* qn = qsT + (size_t)n * NCG * PPL * 8;
  const unsigned short* asrc = wkm + (size_t)(half * 32 + lane31) * 8;

  f32x16 acc = {0.f, 0.f, 0.f, 0.f, 0.f, 0.f, 0.f, 0.f,
                0.f, 0.f, 0.f, 0.f, 0.f, 0.f, 0.f, 0.f};

#pragma unroll
  for (int cb = 0; cb < 16; ++cb) {
    const int cg = 32 + cb * 2 + half;
    const short8 b = *(const short8*)(qn + ((size_t)cg * PPL + psite) * 8);
    const short8 a = *(const short8*)(asrc + (size_t)((mt * 16 + cb) * 2) * 256);
    acc = __builtin_amdgcn_mfma_f32_32x32x16_bf16(a, b, acc, 0, 0, 0);
  }

  float* Dn = D + (size_t)n * MM * HW;
#pragma unroll
  for (int r = 0; r < 16; ++r) {
    const int m = mt * 32 + (r & 3) + 8 * (r >> 2) + 4 * half;
    Dn[(size_t)m * HW + s] = acc[r];
  }
}

// ---------------------------------------------------------------------------
// Kernel 5: combine + sigmoid. One thread per output element. XCD-pinned.
// ---------------------------------------------------------------------------
__global__ __launch_bounds__(256) void deform_combine(
    const float* __restrict__ D, const float* __restrict__ par,
    float* __restrict__ out) {
  const int bid = blockIdx.x;          // 648 = 81 * 8n
  const int n  = bid & 7;              // XCD pin
  const int rr = bid >> 3;             // 0..80
  const int o  = rr / 9;
  const int p  = (rr % 9) * 256 + threadIdx.x;

  const float* Dn = D + (size_t)n * MM * HW;
  const float* pb = par + ((size_t)n * KTAP * HW + p) * 8;

  float s = 0.f;
#pragma unroll
  for (int k = 0; k < KTAP; ++k) {
    const float4 wv = *(const float4*)(pb + (size_t)k * HW * 8);
    const int4  av = *(const int4*)(pb + (size_t)k * HW * 8 + 4);
    const float* base = Dn + (size_t)(k * 9 + o) * HW;
    s += wv.x * base[av.x] + wv.y * base[av.y] +
         wv.z * base[av.z] + wv.w * base[av.w];
  }
  out[((size_t)n * KTAP + o) * HW + p] = 1.f / (1.f + __expf(-s));
}

extern "C" void kernel_launch(void* const* d_in, const int* in_sizes, int n_in,
                              void* d_out, int out_size, void* d_ws, size_t ws_size,
                              hipStream_t stream) {
  const float* support  = (const float*)d_in[0];
  const float* query    = (const float*)d_in[1];
  const float* w_off    = (const float*)d_in[2];
  const float* w_kernel = (const float*)d_in[3];
  float* out = (float*)d_out;

  // ws layout (float units), ~50 MB (ws is ~268 MB per harness poison size):
  // [qsT 22.2MB][par 5.3MB][Wm 0.82MB][wkm 0.1MB][X: offs_part 21.2MB / D 7.1MB]
  float* base = (float*)d_ws;
  unsigned short* qsT = (unsigned short*)base;                  // 8*64*PPL*8 bf16
  float* par = base + (size_t)NN * NCG * PPL * 8 / 2;           // NN*9*HW*8 f
  float* tail = par + (size_t)NN * KTAP * HW * 8;
  unsigned short* Wm  = (unsigned short*)tail;                  // 409600 bf16 = 204800 f
  unsigned short* wkm = (unsigned short*)(tail + 204800);       // 49152 bf16 = 24576 f
  float* X = tail + 204800 + 24576;
  float* offs_part = X;                                         // G1*NSZ f (early)
  float* D = X;                                                 // NN*MM*HW f (late, aliases)

  transpose_prep_kernel<<<9216 + 1696, 256, 0, stream>>>(
      support, query, w_off, w_kernel, qsT, Wm, wkm);
  offset_conv_mfma<<<1536, 192, 0, stream>>>(qsT, Wm, offs_part);
  param_kernel<<<81 * 8, 256, 0, stream>>>(offs_part, par);
  deform_gemm<<<54 * 8, 256, 0, stream>>>(qsT, wkm, D);   // D aliases offs_part (dead)
  deform_combine<<<81 * 8, 256, 0, stream>>>(D, par, out);
}

// Round 19
// 49.743 us; speedup vs baseline: 1.7154x; 1.1427x over previous
//
#include <hip/hip_runtime.h>
#include <math.h>

#define NN 8
#define CC 256        // channels per tensor (concat input has 2*CC = 512)
#define HH 48
#define WW 48
#define HW 2304       // 48*48
#define OCONV 18      // offset-conv output channels (2*K)
#define KTAP 9        // deform taps
#define G1 16         // split-K groups for offset conv (512/16 = 32 ch/group)
#define NSZ (NN * OCONV * HW)   // 331776
#define MM 96         // padded deform-GEMM rows (81 used)
#define NCG 64        // 512 ch / 8
#define PPL 2704      // padded plane sites: 52*52 (2-site zero border)

#define NCONVB 1536   // conv blocks in merged kernel
#define NGEMMB 576    // gemm blocks in merged kernel (3 waves each)

typedef __attribute__((ext_vector_type(8))) short short8;   // 8 bf16 (4 VGPRs)
typedef __attribute__((ext_vector_type(16))) float f32x16;  // 32x32 MFMA acc

static __device__ __forceinline__ unsigned short f2bf(float f) {
  unsigned u = __float_as_uint(f);
  unsigned r = (u + 0x7fffu + ((u >> 16) & 1u)) >> 16;   // round-to-nearest-even
  return (unsigned short)r;
}

// ---------------------------------------------------------------------------
// Kernel 1 (merged): blocks 0..9215 transpose query+support ->
// qsT[n][cg][52x52 padded][8ch] bf16 (2-site zero border, XCD-pinned);
// blocks 9216..10911 do weight prep (Wm conv A-frags, wkm deform A-frags).
// ---------------------------------------------------------------------------
__global__ __launch_bounds__(256) void transpose_prep_kernel(
    const float* __restrict__ support, const float* __restrict__ query,
    const float* __restrict__ w_off, const float* __restrict__ w_kernel,
    unsigned short* __restrict__ qsT, unsigned short* __restrict__ Wm,
    unsigned short* __restrict__ wkm) {
  const int bid = blockIdx.x;
  const int tid = threadIdx.x;

  if (bid >= 9216) {                  // ---- weight prep part ----
    const int b = bid - 9216;
    if (b < 1600) {
      const int i = b * 256 + tid;    // < 409600
      const int j  = i & 7;
      const int o  = (i >> 3) & 31;
      const int cb = (i >> 8) & 63;
      const int t  = i >> 14;
      float v = 0.f;
      if (o < OCONV) v = w_off[(size_t)(o * (2 * CC) + cb * 8 + j) * 25 + t];
      Wm[i] = f2bf(v);
    } else {
      const int i = (b - 1600) * 256 + tid;
      if (i < 3 * 16 * 2 * 32 * 8) {
        const int j    = i & 7;
        const int r    = (i >> 3) & 31;
        const int half = (i >> 8) & 1;
        const int cb   = (i >> 9) & 15;
        const int mt   = i >> 13;
        const int m = mt * 32 + r;
        const int c = cb * 16 + half * 8 + j;
        float v = 0.f;
        if (m < 81) {
          const int k = m / 9, o = m % 9;
          v = w_kernel[(size_t)(o * CC + c) * KTAP + k];
        }
        wkm[i] = f2bf(v);
      }
    }
    return;
  }

  // ---- transpose part (bid 0..9215 = 8n * 72pt * 16ct) ----
  const int n    = bid & 7;           // XCD pin
  const int rest = bid >> 3;
  const int pt = rest % 72;
  const int ct = rest / 72;           // 0..15; 32-ch block
  const int p0 = pt * 32;

  __shared__ float tile[32][33];

  const float* plane = ((ct < 8) ? query : support) +
                       ((size_t)n * CC + (ct & 7) * 32) * HW;
#pragma unroll
  for (int j = 0; j < 4; ++j) {
    const int idx = tid + j * 256;
    const int cc = idx >> 5, pp = idx & 31;
    tile[pp][cc] = plane[(size_t)cc * HW + p0 + pp];
  }
  __syncthreads();

  unsigned short* qn = qsT + (size_t)n * NCG * PPL * 8;
  const int cgbase = ((ct < 8) ? 0 : 32) + (ct & 7) * 4;

  if (tid < 128) {
    const int pp  = tid & 31;
    const int cgl = tid >> 5;          // 0..3
    const int s = p0 + pp;
    const int y = s / 48, x = s % 48;
    const int psite = (y + 2) * 52 + (x + 2);
    const float* row = &tile[pp][cgl * 8];
    uint4 w;
    w.x = (unsigned)f2bf(row[0]) | ((unsigned)f2bf(row[1]) << 16);
    w.y = (unsigned)f2bf(row[2]) | ((unsigned)f2bf(row[3]) << 16);
    w.z = (unsigned)f2bf(row[4]) | ((unsigned)f2bf(row[5]) << 16);
    w.w = (unsigned)f2bf(row[6]) | ((unsigned)f2bf(row[7]) << 16);
    *(uint4*)(qn + ((size_t)(cgbase + cgl) * PPL + psite) * 8) = w;
  }

  // zero border: 400 border sites x 4 cg planes, done by pt==0 blocks
  if (pt == 0) {
    const uint4 zz = make_uint4(0u, 0u, 0u, 0u);
    for (int z = tid; z < 1600; z += 256) {
      const int cgl = z / 400;
      const int e   = z % 400;
      int row, col;
      if (e < 104)      { row = e / 52;              col = e % 52; }          // rows 0,1
      else if (e < 208) { row = 50 + (e - 104) / 52; col = (e - 104) % 52; }  // rows 50,51
      else {
        const int f = e - 208;                                               // cols 0,1,50,51
        row = 2 + f / 4;
        const int cs = f % 4;
        col = (cs < 2) ? cs : (48 + cs);
      }
      *(uint4*)(qn + ((size_t)(cgbase + cgl) * PPL + row * 52 + col) * 8) = zz;
    }
  }
}

// ---------------------------------------------------------------------------
// Kernel 2 (merged): blocks 0..1535 = offset conv (R18 structure: G1=16,
// 26.6KB LDS, asymmetric-depth pipeline, XCD-pinned); blocks 1536..2111 =
// deform GEMM D[n][m][site] (3 waves/block, depends only on qsT/wkm so it
// overlaps conv's tail on the same dispatch). 192 threads/block.
// ---------------------------------------------------------------------------
__global__ __launch_bounds__(192, 2) void conv_gemm_kernel(
    const unsigned short* __restrict__ qsT,
    const unsigned short* __restrict__ Wm,
    const unsigned short* __restrict__ wkm,
    float* __restrict__ offs_part, float* __restrict__ D) {
  const int bid = blockIdx.x;
  const int tid = threadIdx.x;
  const int w = tid >> 6;
  const int l = tid & 63;
  const int l31 = l & 31;
  const int half = l >> 5;

  __shared__ __align__(16) unsigned short lds[1664 * 8];   // 26,624 B (conv only)

  if (bid >= NCONVB) {
    // ---- deform GEMM part: D[n][m][site] = sum_c wk * sup, m=k*9+o ----
    const int b2 = bid - NCONVB;        // 0..575
    const int n    = b2 & 7;            // XCD pin
    const int rest = b2 >> 3;           // 0..71
    const int wid = rest * 3 + w;       // 0..215
    const int st = wid % 72;            // site tile
    const int mt = wid / 72;            // m tile 0..2
    const int s = st * 32 + l31;
    const int psite = (s / 48) * 52 + (s % 48) + 2 * 52 + 2;

    const unsigned short* qn = qsT + (size_t)n * NCG * PPL * 8;
    const unsigned short* asrc = wkm + (size_t)(half * 32 + l31) * 8;

    f32x16 acc = {0.f, 0.f, 0.f, 0.f, 0.f, 0.f, 0.f, 0.f,
                  0.f, 0.f, 0.f, 0.f, 0.f, 0.f, 0.f, 0.f};

#pragma unroll
    for (int cb = 0; cb < 16; ++cb) {
      const int cg = 32 + cb * 2 + half;
      const short8 b = *(const short8*)(qn + ((size_t)cg * PPL + psite) * 8);
      const short8 a = *(const short8*)(asrc + (size_t)((mt * 16 + cb) * 2) * 256);
      acc = __builtin_amdgcn_mfma_f32_32x32x16_bf16(a, b, acc, 0, 0, 0);
    }

    float* Dn = D + (size_t)n * MM * HW;
#pragma unroll
    for (int r = 0; r < 16; ++r) {
      const int m = mt * 32 + (r & 3) + 8 * (r >> 2) + 4 * half;
      Dn[(size_t)m * HW + s] = acc[r];
    }
    return;
  }

  // ---- offset conv part (bid 0..1535 = 12rt * 16g * 8n) ----
  const int n  = bid & 7;            // XCD pin
  const int r2 = bid >> 3;           // 0..191
  const int g  = r2 & 15;            // channel group (32 ch)
  const int rt = r2 >> 4;            // 0..11 (4 image rows each)

  // ---- stage: cg 0..3 (abs g*4+cg), padded rows rt*4..rt*4+7, cols 0..51 ----
  const unsigned short* qn = qsT + ((size_t)n * NCG + g * 4) * PPL * 8;
  for (int c = tid; c < 1664; c += 192) {
    const int cg  = c / 416;
    const int rem = c - cg * 416;                    // rr*52 + col
    const uint4 v = *(const uint4*)(qn + ((size_t)cg * PPL + rt * 4 * 52 + rem) * 8);
    *(uint4*)(lds + (size_t)c * 8) = v;
  }
  __syncthreads();

  const int si0 = w * 64 + l31;      // first site (0..191 within row tile)
  const int si1 = si0 + 32;          // second site
  const int rrA = si0 / 48, xA = si0 % 48;
  const int rrB = si1 / 48, xB = si1 % 48;

  const unsigned short* lbase0 = lds + (half * 416 + rrA * 52 + xA) * 8;
  const unsigned short* lbase1 = lds + (half * 416 + rrB * 52 + xB) * 8;
  const unsigned short* abase = Wm + (size_t)((g * 4 + half) * 32 + l31) * 8;
  // A(t,kk) = abase + t*16384 + kk*512 (shorts); cb = g*4 + kk*2 + half
  // B(t,kk,site) = lbase + kk*6656 + ((t/5)*52 + t%5)*8 (shorts, compile-time)

  f32x16 acc0 = {0.f, 0.f, 0.f, 0.f, 0.f, 0.f, 0.f, 0.f,
                 0.f, 0.f, 0.f, 0.f, 0.f, 0.f, 0.f, 0.f};
  f32x16 acc1 = acc0;

  short8 a[3][2];                    // [t%3][kk] — A prefetched 2 taps ahead
  short8 b0[2][2], b1[2][2];         // [t&1][kk] — B prefetched 1 tap ahead

  // prologue: A taps 0,1; B tap 0
#pragma unroll
  for (int kk = 0; kk < 2; ++kk) {
    a[0][kk]  = *(const short8*)(abase + 0 * 16384 + kk * 512);
    a[1][kk]  = *(const short8*)(abase + 1 * 16384 + kk * 512);
    b0[0][kk] = *(const short8*)(lbase0 + kk * 6656);
    b1[0][kk] = *(const short8*)(lbase1 + kk * 6656);
  }

#pragma unroll
  for (int t = 0; t < 25; ++t) {
    const int bc = t & 1;            // current B buffer
    const int ac = t % 3;            // current A buffer
    if (t < 24) {
      const int tn = t + 1;
      const int loff = ((tn / 5) * 52 + (tn % 5)) * 8;   // compile-time
#pragma unroll
      for (int kk = 0; kk < 2; ++kk) {
        b0[bc ^ 1][kk] = *(const short8*)(lbase0 + kk * 6656 + loff);
        b1[bc ^ 1][kk] = *(const short8*)(lbase1 + kk * 6656 + loff);
      }
    }
    if (t < 23) {
      const int ta = t + 2;
#pragma unroll
      for (int kk = 0; kk < 2; ++kk)
        a[(t + 2) % 3][kk] = *(const short8*)(abase + ta * 16384 + kk * 512);
    }
    __builtin_amdgcn_sched_barrier(0);
#pragma unroll
    for (int kk = 0; kk < 2; ++kk) {
      acc0 = __builtin_amdgcn_mfma_f32_32x32x16_bf16(a[ac][kk], b0[bc][kk], acc0, 0, 0, 0);
      acc1 = __builtin_amdgcn_mfma_f32_32x32x16_bf16(a[ac][kk], b1[bc][kk], acc1, 0, 0, 0);
    }
  }

  float* dst = offs_part + ((size_t)(g * NN + n) * OCONV) * HW;
  const int s0 = rt * 192 + si0;
  const int s1 = rt * 192 + si1;
#pragma unroll
  for (int r = 0; r < 16; ++r) {
    const int o = (r & 3) + 8 * (r >> 2) + 4 * half;
    if (o < OCONV) {
      dst[(size_t)o * HW + s0] = acc0[r];
      dst[(size_t)o * HW + s1] = acc1[r];
    }
  }
}

// ---------------------------------------------------------------------------
// Kernel 3: fold split-K partials + precompute bilinear params.
// par[n][k][p][8]: {w00,w01,w10,w11 (f32), a00,a01,a10,a11 (int)}. XCD-pinned.
// ---------------------------------------------------------------------------
__global__ __launch_bounds__(256) void param_kernel(
    const float* __restrict__ offs_part, float* __restrict__ par) {
  const int n  = blockIdx.x & 7;       // XCD pin
  const int j  = blockIdx.x >> 3;      // 0..80
  const int il = j * 256 + threadIdx.x;
  const int p = il % HW;
  const int k = il / HW;
  const int y = p / WW, x = p % WW;

  float dy = 0.f, dx = 0.f;
#pragma unroll
  for (int g = 0; g < G1; ++g) {
    const float* base = offs_part + ((size_t)(g * NN + n) * OCONV + 2 * k) * HW + p;
    dy += base[0];
    dx += base[HW];
  }
  const float sy = (float)(y + k / 3 - 1) + dy;
  const float sx = (float)(x + k % 3 - 1) + dx;
  const float y0 = floorf(sy), x0 = floorf(sx);
  const float ly = sy - y0,  lx = sx - x0;
  const float y1 = y0 + 1.f, x1 = x0 + 1.f;
  const float vy0 = (y0 >= 0.f && y0 <= (float)(HH - 1)) ? 1.f : 0.f;
  const float vy1 = (y1 >= 0.f && y1 <= (float)(HH - 1)) ? 1.f : 0.f;
  const float vx0 = (x0 >= 0.f && x0 <= (float)(WW - 1)) ? 1.f : 0.f;
  const float vx1 = (x1 >= 0.f && x1 <= (float)(WW - 1)) ? 1.f : 0.f;
  const int yi0 = min(max((int)y0, 0), HH - 1);
  const int yi1 = min(max((int)y1, 0), HH - 1);
  const int xi0 = min(max((int)x0, 0), WW - 1);
  const int xi1 = min(max((int)x1, 0), WW - 1);

  float* d = par + ((size_t)n * KTAP * HW + il) * 8;
  d[0] = (1.f - ly) * (1.f - lx) * vy0 * vx0;
  d[1] = (1.f - ly) * lx * vy0 * vx1;
  d[2] = ly * (1.f - lx) * vy1 * vx0;
  d[3] = ly * lx * vy1 * vx1;
  int* di = (int*)d;
  di[4] = yi0 * WW + xi0;
  di[5] = yi0 * WW + xi1;
  di[6] = yi1 * WW + xi0;
  di[7] = yi1 * WW + xi1;
}

// ---------------------------------------------------------------------------
// Kernel 4: combine + sigmoid. One thread per output element. XCD-pinned.
// ---------------------------------------------------------------------------
__global__ __launch_bounds__(256) void deform_combine(
    const float* __restrict__ D, const float* __restrict__ par,
    float* __restrict__ out) {
  const int bid = blockIdx.x;          // 648 = 81 * 8n
  const int n  = bid & 7;              // XCD pin
  const int rr = bid >> 3;             // 0..80
  const int o  = rr / 9;
  const int p  = (rr % 9) * 256 + threadIdx.x;

  const float* Dn = D + (size_t)n * MM * HW;
  const float* pb = par + ((size_t)n * KTAP * HW + p) * 8;

  float s = 0.f;
#pragma unroll
  for (int k = 0; k < KTAP; ++k) {
    const float4 wv = *(const float4*)(pb + (size_t)k * HW * 8);
    const int4  av = *(const int4*)(pb + (size_t)k * HW * 8 + 4);
    const float* base = Dn + (size_t)(k * 9 + o) * HW;
    s += wv.x * base[av.x] + wv.y * base[av.y] +
         wv.z * base[av.z] + wv.w * base[av.w];
  }
  out[((size_t)n * KTAP + o) * HW + p] = 1.f / (1.f + __expf(-s));
}

extern "C" void kernel_launch(void* const* d_in, const int* in_sizes, int n_in,
                              void* d_out, int out_size, void* d_ws, size_t ws_size,
                              hipStream_t stream) {
  const float* support  = (const float*)d_in[0];
  const float* query    = (const float*)d_in[1];
  const float* w_off    = (const float*)d_in[2];
  const float* w_kernel = (const float*)d_in[3];
  float* out = (float*)d_out;

  // ws layout (float units), ~46 MB (no aliasing; ws is ~268 MB):
  // [qsT 22.2MB][par 5.3MB][Wm 0.82MB][wkm 0.1MB][offs_part 21.2MB][D 7.1MB]
  float* base = (float*)d_ws;
  unsigned short* qsT = (unsigned short*)base;                  // 8*64*PPL*8 bf16
  float* par = base + (size_t)NN * NCG * PPL * 8 / 2;           // NN*9*HW*8 f
  float* tail = par + (size_t)NN * KTAP * HW * 8;
  unsigned short* Wm  = (unsigned short*)tail;                  // 409600 bf16 = 204800 f
  unsigned short* wkm = (unsigned short*)(tail + 204800);       // 49152 bf16 = 24576 f
  float* offs_part = tail + 204800 + 24576;                     // G1*NSZ f
  float* D = offs_part + (size_t)G1 * NSZ;                      // NN*MM*HW f

  transpose_prep_kernel<<<9216 + 1696, 256, 0, stream>>>(
      support, query, w_off, w_kernel, qsT, Wm, wkm);
  conv_gemm_kernel<<<NCONVB + NGEMMB, 192, 0, stream>>>(qsT, Wm, wkm, offs_part, D);
  param_kernel<<<81 * 8, 256, 0, stream>>>(offs_part, par);
  deform_combine<<<81 * 8, 256, 0, stream>>>(D, par, out);
}